// Round 5
// baseline (1458.365 us; speedup 1.0000x reference)
//
#include <hip/hip_runtime.h>

#define NN 50000
#define NE 500000
#define HD 128

typedef _Float16 f16;
typedef _Float16 f16x8 __attribute__((ext_vector_type(8)));
typedef _Float16 f16x4 __attribute__((ext_vector_type(4)));
typedef float f32x4 __attribute__((ext_vector_type(4)));

// ---------- helpers ----------

// XOR-swizzled LDS index for a [rows][128] f16 tile (16B-chunk swizzle, no pad).
__device__ __forceinline__ int swz(int r, int c) {
  return r * HD + ((((c >> 3) ^ r) & 15) << 3) + (c & 7);
}

__device__ __forceinline__ float fast_silu(float x) {
  return x * __builtin_amdgcn_rcpf(1.0f + __expf(-x));
}

// One wave computes a 32x64 sub-tile of D(64x128) = A(64x128) @ W^T. (256-thr blocks)
__device__ __forceinline__ void gemm_wave_g(const f16* A, const f16* __restrict__ Wg,
                                            int wstride, int rowBase, int colBase,
                                            f32x4 acc[2][4]) {
  const int lane = (int)threadIdx.x & 63;
  const int m = lane & 15;
  const int q = lane >> 4;
#pragma unroll
  for (int kc = 0; kc < 4; ++kc) {
    const int pc = (((kc * 4 + q) ^ m) & 15) << 3;  // swizzled A k-chunk offset
    const int gk = (kc * 4 + q) << 3;               // linear k offset for global W
    f16x8 a0 = *(const f16x8*)(A + (rowBase + m) * HD + pc);
    f16x8 a1 = *(const f16x8*)(A + (rowBase + 16 + m) * HD + pc);
#pragma unroll
    for (int ct = 0; ct < 4; ++ct) {
      f16x8 b = *(const f16x8*)(Wg + (colBase + ct * 16 + m) * wstride + gk);
      acc[0][ct] = __builtin_amdgcn_mfma_f32_16x16x32_f16(a0, b, acc[0][ct], 0, 0, 0);
      acc[1][ct] = __builtin_amdgcn_mfma_f32_16x16x32_f16(a1, b, acc[1][ct], 0, 0, 0);
    }
  }
}

// One wave computes a 32x32 sub-tile (512-thread blocks, 8 waves over 64x128).
__device__ __forceinline__ void gemm_wave_g2(const f16* A, const f16* __restrict__ Wg,
                                             int wstride, int rowBase, int colBase,
                                             f32x4 acc[2][2]) {
  const int lane = (int)threadIdx.x & 63;
  const int m = lane & 15;
  const int q = lane >> 4;
#pragma unroll
  for (int kc = 0; kc < 4; ++kc) {
    const int pc = (((kc * 4 + q) ^ m) & 15) << 3;
    const int gk = (kc * 4 + q) << 3;
    f16x8 a0 = *(const f16x8*)(A + (rowBase + m) * HD + pc);
    f16x8 a1 = *(const f16x8*)(A + (rowBase + 16 + m) * HD + pc);
#pragma unroll
    for (int ct = 0; ct < 2; ++ct) {
      f16x8 b = *(const f16x8*)(Wg + (colBase + ct * 16 + m) * wstride + gk);
      acc[0][ct] = __builtin_amdgcn_mfma_f32_16x16x32_f16(a0, b, acc[0][ct], 0, 0, 0);
      acc[1][ct] = __builtin_amdgcn_mfma_f32_16x16x32_f16(a1, b, acc[1][ct], 0, 0, 0);
    }
  }
}

#define ZACC(acc)                                        \
  {                                                      \
    _Pragma("unroll") for (int zi = 0; zi < 2; ++zi)     \
        _Pragma("unroll") for (int zj = 0; zj < 4; ++zj) \
            acc[zi][zj] = (f32x4){0.f, 0.f, 0.f, 0.f};   \
  }

#define ZACC2(acc)                                       \
  {                                                      \
    _Pragma("unroll") for (int zi = 0; zi < 2; ++zi)     \
        _Pragma("unroll") for (int zj = 0; zj < 2; ++zj) \
            acc[zi][zj] = (f32x4){0.f, 0.f, 0.f, 0.f};   \
  }

// cooperative 64x128 f16 tile: global(row-major, stride HD) <-> swizzled LDS
template <int TPB>
__device__ __forceinline__ void stage_rows64(const f16* __restrict__ g, long r0,
                                             long lim, f16* lds) {
#pragma unroll
  for (int it = 0; it < 1024 / TPB; ++it) {
    int idx = it * TPB + (int)threadIdx.x;
    int r = idx >> 4, ck = idx & 15;
    f16x8 v = {};
    if (r0 + r < lim) v = *(const f16x8*)(g + (r0 + r) * HD + ck * 8);
    *(f16x8*)(lds + r * HD + (((ck ^ r) & 15) << 3)) = v;
  }
}
template <int TPB>
__device__ __forceinline__ void store_rows64(const f16* lds, f16* __restrict__ g,
                                             long r0, long lim) {
#pragma unroll
  for (int it = 0; it < 1024 / TPB; ++it) {
    int idx = it * TPB + (int)threadIdx.x;
    int r = idx >> 4, ck = idx & 15;
    if (r0 + r < lim)
      *(f16x8*)(g + (r0 + r) * HD + ck * 8) =
          *(const f16x8*)(lds + r * HD + (((ck ^ r) & 15) << 3));
  }
}

// ---------- weight prep (fp32 (in,out) -> f16 [out][in]) ----------
struct TJob {
  const float* src;
  f16* dst;
  int idim;
  int odim;
};
struct TJobs {
  TJob j[27];
};

__global__ __launch_bounds__(256) void k_prep(TJobs jobs) {
  int job = blockIdx.x >> 2;
  int part = blockIdx.x & 3;
  TJob J = jobs.j[job];
  int total = J.idim * J.odim;
  for (int idx = part * 256 + (int)threadIdx.x; idx < total; idx += 1024) {
    int o = idx / J.idim;
    int i = idx - o * J.idim;
    J.dst[idx] = (f16)J.src[(long)i * J.odim + o];
  }
}

// Wee1 (4x128 f32) -> f16 [128][8] zero-padded to K=8
__global__ __launch_bounds__(128) void k_prep_E(const float* __restrict__ W,
                                                f16* __restrict__ W8) {
  int t = threadIdx.x;
#pragma unroll
  for (int i = 0; i < 8; ++i) W8[t * 8 + i] = (i < 4) ? (f16)W[i * 128 + t] : (f16)0.f;
}

// ---------- folded edge-encoder weights ----------
// Mt[l][o][h] = sum_e Wee2[h][e] * We1[l][2H+e][o]   (f16, [out][in] layout)
// cv[l][o]   = sum_e b2[e]      * We1[l][2H+e][o]   (f32)
__global__ __launch_bounds__(128) void k_prep_M(const float* __restrict__ Wee2,
                                                const float* __restrict__ b2,
                                                const float* __restrict__ We1,
                                                f16* __restrict__ Mt,
                                                float* __restrict__ cv) {
  __shared__ float col[128];
  int l = blockIdx.x >> 7, o = blockIdx.x & 127;
  int t = threadIdx.x;
  col[t] = We1[((size_t)l * 384 + 256 + t) * 128 + o];
  __syncthreads();
  float s = 0.f;
#pragma unroll 8
  for (int e = 0; e < 128; ++e) s += Wee2[t * 128 + e] * col[e];
  Mt[((size_t)l * 128 + o) * 128 + t] = (f16)s;
  if (t == 0) {
    float c = 0.f;
    for (int e = 0; e < 128; ++e) c += b2[e] * col[e];
    cv[l * 128 + o] = c;
  }
}

// ---------- folded aggregation weights ----------
// WZ[l] = We2[l] @ Wn1_agg[l]  (agg rows 128..255 of Wn1), stored f16 [out][in]
// bv[l][o] = sum_j be2[l][j] * Wn1[l][128+j][o]  (f32)
__global__ __launch_bounds__(128) void k_prep_Z(const float* __restrict__ We2,
                                                const float* __restrict__ be2,
                                                const float* __restrict__ Wn1,
                                                f16* __restrict__ WZt,
                                                float* __restrict__ bve) {
  __shared__ float col[128];
  int l = blockIdx.x >> 7, o = blockIdx.x & 127;
  int t = threadIdx.x;
  col[t] = Wn1[((size_t)l * 256 + 128 + t) * 128 + o];
  __syncthreads();
  float s = 0.f;
#pragma unroll 8
  for (int j = 0; j < 128; ++j) s += We2[(size_t)l * 128 * 128 + t * 128 + j] * col[j];
  WZt[((size_t)l * 128 + o) * 128 + t] = (f16)s;
  if (t == 0) {
    float c = 0.f;
    for (int j = 0; j < 128; ++j) c += be2[l * 128 + j] * col[j];
    bve[l * 128 + o] = c;
  }
}

// ---------- counting sort by dst ----------
__global__ __launch_bounds__(256) void k_hist(const int* __restrict__ dst,
                                              int* __restrict__ count) {
  int e = blockIdx.x * 256 + threadIdx.x;
  if (e < NE) atomicAdd(&count[dst[e]], 1);
}

__global__ __launch_bounds__(1024) void k_scan(const int* __restrict__ count,
                                               int* __restrict__ startA) {
  __shared__ int lds[1024];
  const int CH = 49;  // 49*1024 >= NN
  int t = threadIdx.x;
  int b = t * CH;
  int e = b + CH < NN ? b + CH : NN;
  int s = 0;
  for (int i = b; i < e; ++i) s += count[i];
  lds[t] = s;
  __syncthreads();
  for (int off = 1; off < 1024; off <<= 1) {
    int v = (t >= off) ? lds[t - off] : 0;
    __syncthreads();
    lds[t] += v;
    __syncthreads();
  }
  int run = lds[t] - s;  // exclusive prefix of this chunk
  for (int i = b; i < e; ++i) {
    startA[i] = run;
    run += count[i];
  }
  if (t == 0) startA[NN] = NE;
}

__global__ __launch_bounds__(256) void k_scatter(const int* __restrict__ src,
                                                 const int* __restrict__ dst,
                                                 const float* __restrict__ coords,
                                                 const int* __restrict__ startA,
                                                 int* __restrict__ cursor,
                                                 int* __restrict__ srcS,
                                                 int* __restrict__ dstS,
                                                 f16* __restrict__ efS) {
  int e = blockIdx.x * 256 + threadIdx.x;
  if (e >= NE) return;
  int s = src[e];
  int n = dst[e];
  int pos = startA[n] + atomicAdd(&cursor[n], 1);
  srcS[pos] = s;
  dstS[pos] = n;
  float rx = coords[n * 3] - coords[s * 3];
  float ry = coords[n * 3 + 1] - coords[s * 3 + 1];
  float rz = coords[n * 3 + 2] - coords[s * 3 + 2];
  float nr = sqrtf(rx * rx + ry * ry + rz * rz);
  f16x8 v = {};
  v[0] = (f16)rx;
  v[1] = (f16)ry;
  v[2] = (f16)rz;
  v[3] = (f16)nr;
  *(f16x8*)(efS + (long)pos * 8) = v;
}

// ---------- node encoder: h = silu(x@Wne1+b)@Wne2+b ; also layer-0 Pd/Ps ----------
__global__ __launch_bounds__(256, 4) void k_enc_node(
    const float* __restrict__ x, const float* __restrict__ W1,
    const float* __restrict__ b1, const f16* __restrict__ W2t,
    const float* __restrict__ b2, const f16* __restrict__ We1t0,
    const float* __restrict__ be10, const float* __restrict__ cvec0,
    float* __restrict__ h32, f16* __restrict__ h16, f16* __restrict__ Pd,
    f16* __restrict__ Ps) {
  __shared__ __align__(16) f16 lds_A[64 * HD];
  __shared__ __align__(16) f16 lds_O[64 * HD];
  float* lds_x = (float*)lds_O;  // alias O
  long r0 = (long)blockIdx.x * 64;
  int t = threadIdx.x;
  int wv = t >> 6, lane = t & 63, nn = lane & 15, q = lane >> 4;
  int rowBase = (wv >> 1) * 32, colBase = (wv & 1) * 64;

  if (t < 192) {
    long i = r0 * 3 + t;
    lds_x[t] = (i < (long)NN * 3) ? x[i] : 0.f;
  }
  __syncthreads();

  for (int it = 0; it < 32; ++it) {
    int idx = it * 256 + t;
    int r = idx >> 7, c = idx & 127;
    float a = b1[c];
    a += lds_x[r * 3 + 0] * W1[0 * HD + c];
    a += lds_x[r * 3 + 1] * W1[1 * HD + c];
    a += lds_x[r * 3 + 2] * W1[2 * HD + c];
    lds_A[swz(r, c)] = (f16)fast_silu(a);
  }
  __syncthreads();

  f32x4 acc[2][4];
  ZACC(acc);
  gemm_wave_g(lds_A, W2t, HD, rowBase, colBase, acc);
#pragma unroll
  for (int rt = 0; rt < 2; ++rt)
#pragma unroll
    for (int ct = 0; ct < 4; ++ct)
#pragma unroll
      for (int rg = 0; rg < 4; ++rg) {
        int row = rowBase + rt * 16 + q * 4 + rg;
        int col = colBase + ct * 16 + nn;
        float v = acc[rt][ct][rg] + b2[col];
        long nr = r0 + row;
        if (nr < NN) h32[nr * HD + col] = v;
        lds_O[swz(row, col)] = (f16)v;
      }
  __syncthreads();  // lds_O (h) complete; lds_A free (all waves past GEMM)
  store_rows64<256>(lds_O, h16, r0, NN);

  // layer-0 Pd = h@W_d + be1 + cv -> via lds_A
  ZACC(acc);
  gemm_wave_g(lds_O, We1t0, 384, rowBase, colBase, acc);
#pragma unroll
  for (int rt = 0; rt < 2; ++rt)
#pragma unroll
    for (int ct = 0; ct < 4; ++ct)
#pragma unroll
      for (int rg = 0; rg < 4; ++rg) {
        int row = rowBase + rt * 16 + q * 4 + rg;
        int col = colBase + ct * 16 + nn;
        lds_A[swz(row, col)] = (f16)(acc[rt][ct][rg] + be10[col] + cvec0[col]);
      }
  __syncthreads();
  store_rows64<256>(lds_A, Pd, r0, NN);

  // layer-0 Ps = h@W_s
  ZACC(acc);
  gemm_wave_g(lds_O, We1t0 + 128, 384, rowBase, colBase, acc);
  __syncthreads();  // all waves done store-reading lds_A (Pd)
#pragma unroll
  for (int rt = 0; rt < 2; ++rt)
#pragma unroll
    for (int ct = 0; ct < 4; ++ct)
#pragma unroll
      for (int rg = 0; rg < 4; ++rg) {
        int row = rowBase + rt * 16 + q * 4 + rg;
        int col = colBase + ct * 16 + nn;
        lds_A[swz(row, col)] = (f16)acc[rt][ct][rg];
      }
  __syncthreads();
  store_rows64<256>(lds_A, Ps, r0, NN);
}

// ---------- per-layer edge kernel (512 thr, 8 waves) ----------
// z = silu(silu2@Mt + Pd[dst]+Ps[src]); silu2 computed via K=8-packed MFMA.
// Segmented z-sum: plain store for quarter-interior runs, atomic at boundaries.
__global__ __launch_bounds__(512, 8) void k_edge(
    const f16* __restrict__ efS, const int* __restrict__ srcS,
    const int* __restrict__ dstS, const f16* __restrict__ Pd,
    const f16* __restrict__ Ps, const f16* __restrict__ W1e8,
    const float* __restrict__ b1, const f16* __restrict__ Mt,
    float* __restrict__ zs, int nwg) {
  __shared__ __align__(16) f16 lds_A[64 * HD];  // silu2
  __shared__ __align__(16) f16 lds_P[64 * HD];  // pdps, then z
  __shared__ int dstL[64];
  // bijective XCD-chunked swizzle: consecutive logical blocks -> same XCD
  int orig = blockIdx.x;
  int xcd = orig & 7, loc = orig >> 3;
  int qq = nwg >> 3, rr = nwg & 7;
  int wg = (xcd < rr ? xcd * (qq + 1) : rr * (qq + 1) + (xcd - rr) * qq) + loc;
  long e0 = (long)wg * 64;
  int t = threadIdx.x;
  int lane = t & 63, nn = lane & 15, q = lane >> 4;
  int wv = t >> 6;
  int rowBase = (wv >> 2) * 32, colBase = (wv & 3) * 32;

  if (t < 64) {
    long e = e0 + t;
    dstL[t] = (e < NE) ? dstS[e] : -1;
  }

  // silu2 A/B fragments: only q==0 lanes carry k=0..7 (ef padded 4->8)
  f16x8 ea0 = {}, ea1 = {}, eb0 = {}, eb1 = {};
  if (q == 0) {
    long er0 = e0 + rowBase + nn;
    long er1 = er0 + 16;
    if (er0 < NE) ea0 = *(const f16x8*)(efS + er0 * 8);
    if (er1 < NE) ea1 = *(const f16x8*)(efS + er1 * 8);
    eb0 = *(const f16x8*)(W1e8 + (colBase + nn) * 8);
    eb1 = *(const f16x8*)(W1e8 + (colBase + 16 + nn) * 8);
  }
  f32x4 sacc[2][2];
  ZACC2(sacc);
  sacc[0][0] = __builtin_amdgcn_mfma_f32_16x16x32_f16(ea0, eb0, sacc[0][0], 0, 0, 0);
  sacc[1][0] = __builtin_amdgcn_mfma_f32_16x16x32_f16(ea1, eb0, sacc[1][0], 0, 0, 0);
  sacc[0][1] = __builtin_amdgcn_mfma_f32_16x16x32_f16(ea0, eb1, sacc[0][1], 0, 0, 0);
  sacc[1][1] = __builtin_amdgcn_mfma_f32_16x16x32_f16(ea1, eb1, sacc[1][1], 0, 0, 0);

  // pdps gathers -> registers (latency hidden under silu2 epilogue)
  int rr0 = t >> 4, rr1 = 32 + (t >> 4);
  int ck = t & 15;
  f16x8 pa0 = {}, pb0 = {}, pa1 = {}, pb1 = {};
  {
    long e = e0 + rr0;
    if (e < NE) {
      int d = dstS[e], s = srcS[e];
      pa0 = *(const f16x8*)(Pd + (long)d * HD + ck * 8);
      pb0 = *(const f16x8*)(Ps + (long)s * HD + ck * 8);
    }
  }
  {
    long e = e0 + rr1;
    if (e < NE) {
      int d = dstS[e], s = srcS[e];
      pa1 = *(const f16x8*)(Pd + (long)d * HD + ck * 8);
      pb1 = *(const f16x8*)(Ps + (long)s * HD + ck * 8);
    }
  }

  // silu2 epilogue -> lds_A (swizzled, f16)
  {
    float b1v0 = b1[colBase + nn], b1v1 = b1[colBase + 16 + nn];
#pragma unroll
    for (int rt = 0; rt < 2; ++rt)
#pragma unroll
      for (int ct = 0; ct < 2; ++ct) {
        float bb = ct ? b1v1 : b1v0;
        int col = colBase + ct * 16 + nn;
#pragma unroll
        for (int rg = 0; rg < 4; ++rg) {
          int row = rowBase + rt * 16 + q * 4 + rg;
          lds_A[swz(row, col)] = (f16)fast_silu(sacc[rt][ct][rg] + bb);
        }
      }
  }
  // pdps -> lds_P
  {
    f16x8 v = pa0 + pb0;
    *(f16x8*)(lds_P + rr0 * HD + (((ck ^ rr0) & 15) << 3)) = v;
  }
  {
    f16x8 v = pa1 + pb1;
    *(f16x8*)(lds_P + rr1 * HD + (((ck ^ rr1) & 15) << 3)) = v;
  }
  __syncthreads();

  f32x4 acc[2][2];
  ZACC2(acc);
  gemm_wave_g2(lds_A, Mt, HD, rowBase, colBase, acc);  // silu2 @ Mt[l]

  // z = silu(acc + pdps) in-place into OWN 32x32 region of lds_P (cv in Pd)
#pragma unroll
  for (int rt = 0; rt < 2; ++rt)
#pragma unroll
    for (int ct = 0; ct < 2; ++ct)
#pragma unroll
      for (int rg = 0; rg < 4; ++rg) {
        int row = rowBase + rt * 16 + q * 4 + rg;
        int col = colBase + ct * 16 + nn;
        float v = acc[rt][ct][rg] + (float)lds_P[swz(row, col)];
        lds_P[swz(row, col)] = (f16)fast_silu(v);
      }
  __syncthreads();

  // segmented z-sum over sorted dst runs; quarter-interior runs: plain store
  {
    int c = t & 127, qt = t >> 7;
    int rb = qt * 16;
    int dfirst = dstL[rb], dlast = dstL[rb + 15];
    int prev = dfirst;
    float sum = 0.f;
    for (int r = rb; r < rb + 16; ++r) {
      int d = dstL[r];
      if (d != prev) {
        if (prev >= 0) {
          if (prev == dfirst || prev == dlast)
            atomicAdd(&zs[(long)prev * HD + c], sum);
          else
            zs[(long)prev * HD + c] = sum;  // sole writer for interior run
        }
        sum = 0.f;
        prev = d;
      }
      sum += (float)lds_P[swz(r, c)];
    }
    if (prev >= 0) atomicAdd(&zs[(long)prev * HD + c], sum);
  }
}

// ---------- per-layer node kernel (512 thr): upd MLP + residual + LayerNorm,
// then Pd/Ps for the NEXT layer from the fresh y tile (k_pp fused). ----------
__global__ __launch_bounds__(512, 6) void k_node(
    const f16* __restrict__ h16in, float* __restrict__ zsum,
    const int* __restrict__ startA, const f16* __restrict__ Wn1t,
    const float* __restrict__ bn1, const f16* __restrict__ WZt,
    const float* __restrict__ bve, const f16* __restrict__ Wn2t,
    const float* __restrict__ bn2, const float* __restrict__ lg,
    const float* __restrict__ lb, const f16* __restrict__ We1tN,
    const float* __restrict__ be1N, const float* __restrict__ cvecN,
    float* __restrict__ h32, f16* __restrict__ h16out, f16* __restrict__ Pd,
    f16* __restrict__ Ps, int doPP) {
  __shared__ __align__(16) f16 lds_A[64 * HD];  // h, then y
  __shared__ __align__(16) f16 lds_B[64 * HD];  // zbar, then z, then Pd/Ps staging
  __shared__ float lds_s[512];
  __shared__ float degf[64];
  long r0 = (long)blockIdx.x * 64;
  int t = threadIdx.x;
  int wv = t >> 6, lane = t & 63, nn = lane & 15, q = lane >> 4;
  int rowBase = (wv >> 2) * 32, colBase = (wv & 3) * 32;

  stage_rows64<512>(h16in, r0, NN, lds_A);
  // zbar = zsum / max(deg,1) -> f16 ; zero zsum for next layer
#pragma unroll
  for (int it = 0; it < 4; ++it) {
    int idx = it * 512 + t;
    int r = idx >> 5, c4 = (idx & 31) * 4;
    long nr = r0 + r;
    f16x4 v = {};
    if (nr < NN) {
      float deg = (float)(startA[nr + 1] - startA[nr]);
      float inv = __builtin_amdgcn_rcpf(fmaxf(deg, 1.0f));
      float4 a = *(const float4*)(zsum + nr * HD + c4);
      *(float4*)(zsum + nr * HD + c4) = (float4){0.f, 0.f, 0.f, 0.f};
      v[0] = (f16)(a.x * inv);
      v[1] = (f16)(a.y * inv);
      v[2] = (f16)(a.z * inv);
      v[3] = (f16)(a.w * inv);
      if (c4 == 0) degf[r] = deg > 0.f ? 1.f : 0.f;
    } else if (c4 == 0) {
      degf[r] = 0.f;
    }
    *(f16x4*)(lds_B + swz(r, c4)) = v;
  }
  __syncthreads();

  f32x4 acc[2][2];
  ZACC2(acc);
  gemm_wave_g2(lds_A, Wn1t, 256, rowBase, colBase, acc);  // h part
  gemm_wave_g2(lds_B, WZt, HD, rowBase, colBase, acc);    // zbar part (We2 folded)
  __syncthreads();  // all waves done reading lds_B before z overwrite

  // z = silu(acc + bn1 + [deg>0]*bv) -> lds_B
#pragma unroll
  for (int rt = 0; rt < 2; ++rt)
#pragma unroll
    for (int ct = 0; ct < 2; ++ct)
#pragma unroll
      for (int rg = 0; rg < 4; ++rg) {
        int row = rowBase + rt * 16 + q * 4 + rg;
        int col = colBase + ct * 16 + nn;
        lds_B[swz(row, col)] =
            (f16)fast_silu(acc[rt][ct][rg] + bn1[col] + degf[row] * bve[col]);
      }
  __syncthreads();

  ZACC2(acc);
  gemm_wave_g2(lds_B, Wn2t, HD, rowBase, colBase, acc);

  // residual + LN stats
  float vv[2][2][4];
  float s1[8], s2[8];
#pragma unroll
  for (int i = 0; i < 8; ++i) {
    s1[i] = 0.f;
    s2[i] = 0.f;
  }
#pragma unroll
  for (int rt = 0; rt < 2; ++rt)
#pragma unroll
    for (int ct = 0; ct < 2; ++ct)
#pragma unroll
      for (int rg = 0; rg < 4; ++rg) {
        int row = rowBase + rt * 16 + q * 4 + rg;
        int col = colBase + ct * 16 + nn;
        long nr = r0 + row;
        float hv = (nr < NN) ? h32[nr * HD + col] : 0.f;
        float v = acc[rt][ct][rg] + bn2[col] + hv;
        vv[rt][ct][rg] = v;
        s1[rt * 4 + rg] += v;
        s2[rt * 4 + rg] += v * v;
      }
#pragma unroll
  for (int msk = 1; msk <= 8; msk <<= 1) {
#pragma unroll
    for (int i = 0; i < 8; ++i) {
      s1[i] += __shfl_xor(s1[i], msk, 64);
      s2[i] += __shfl_xor(s2[i], msk, 64);
    }
  }
  int ch = wv & 3;
  if (nn == 0) {
#pragma unroll
    for (int rt = 0; rt < 2; ++rt)
#pragma unroll
      for (int rg = 0; rg < 4; ++rg) {
        int row = rowBase + rt * 16 + q * 4 + rg;
        lds_s[row * 4 + ch] = s1[rt * 4 + rg];
        lds_s[256 + row * 4 + ch] = s2[rt * 4 + rg];
      }
  }
  __syncthreads();
#pragma unroll
  for (int rt = 0; rt < 2; ++rt)
#pragma unroll
    for (int ct = 0; ct < 2; ++ct)
#pragma unroll
      for (int rg = 0; rg < 4; ++rg) {
        int row = rowBase + rt * 16 + q * 4 + rg;
        int col = colBase + ct * 16 + nn;
        long nr = r0 + row;
        float S1 = lds_s[row * 4] + lds_s[row * 4 + 1] + lds_s[row * 4 + 2] +
                   lds_s[row * 4 + 3];
        float S2 = lds_s[256 + row * 4] + lds_s[256 + row * 4 + 1] +
                   lds_s[256 + row * 4 + 2] + lds_s[256 + row * 4 + 3];
        float mean = S1 * (1.0f / 128.0f);
        float var = S2 * (1.0f / 128.0f) - mean * mean;
        float rstd = rsqrtf(var + 1e-5f);
        float y = (vv[rt][ct][rg] - mean) * rstd * lg[col] + lb[col];
        if (nr < NN) h32[nr * HD + col] = y;
        lds_A[swz(row, col)] = (f16)y;
      }
  __syncthreads();  // y tile complete in lds_A
  store_rows64<512>(lds_A, h16out, r0, NN);

  if (doPP) {
    // Pd(next) = y@W_d + be1 + cv
    ZACC2(acc);
    gemm_wave_g2(lds_A, We1tN, 384, rowBase, colBase, acc);
#pragma unroll
    for (int rt = 0; rt < 2; ++rt)
#pragma unroll
      for (int ct = 0; ct < 2; ++ct)
#pragma unroll
        for (int rg = 0; rg < 4; ++rg) {
          int row = rowBase + rt * 16 + q * 4 + rg;
          int col = colBase + ct * 16 + nn;
          lds_B[swz(row, col)] = (f16)(acc[rt][ct][rg] + be1N[col] + cvecN[col]);
        }
    __syncthreads();
    store_rows64<512>(lds_B, Pd, r0, NN);

    // Ps(next) = y@W_s
    ZACC2(acc);
    gemm_wave_g2(lds_A, We1tN + 128, 384, rowBase, colBase, acc);
    __syncthreads();  // all waves done store-reading lds_B (Pd)
#pragma unroll
    for (int rt = 0; rt < 2; ++rt)
#pragma unroll
      for (int ct = 0; ct < 2; ++ct)
#pragma unroll
        for (int rg = 0; rg < 4; ++rg) {
          int row = rowBase + rt * 16 + q * 4 + rg;
          int col = colBase + ct * 16 + nn;
          lds_B[swz(row, col)] = (f16)acc[rt][ct][rg];
        }
    __syncthreads();
    store_rows64<512>(lds_B, Ps, r0, NN);
  }
}

// ---------- decoder ----------
__global__ __launch_bounds__(256, 4) void k_dec(
    const f16* __restrict__ h16, const f16* __restrict__ Wd1t,
    const float* __restrict__ bd1, const float* __restrict__ Wd2,
    const float* __restrict__ bd2, float* __restrict__ out) {
  __shared__ __align__(16) f16 lds_A[64 * HD];
  __shared__ __align__(16) f16 lds_O[64 * HD];
  long r0 = (long)blockIdx.x * 64;
  int t = threadIdx.x;
  int wv = t >> 6, lane = t & 63, nn = lane & 15, q = lane >> 4;
  int rowBase = (wv >> 1) * 32, colBase = (wv & 1) * 64;

  stage_rows64<256>(h16, r0, NN, lds_A);
  __syncthreads();

  f32x4 acc[2][4];
  ZACC(acc);
  gemm_wave_g(lds_A, Wd1t, HD, rowBase, colBase, acc);
#pragma unroll
  for (int rt = 0; rt < 2; ++rt)
#pragma unroll
    for (int ct = 0; ct < 4; ++ct)
#pragma unroll
      for (int rg = 0; rg < 4; ++rg) {
        int row = rowBase + rt * 16 + q * 4 + rg;
        int col = colBase + ct * 16 + nn;
        lds_O[swz(row, col)] = (f16)fast_silu(acc[rt][ct][rg] + bd1[col]);
      }
  __syncthreads();

  for (int idx = t; idx < 64 * 9; idx += 256) {
    int r = idx / 9;
    int o = idx - r * 9;
    long nr = r0 + r;
    if (nr < NN) {
      float a = bd2[o];
      for (int k = 0; k < 128; ++k) a += (float)lds_O[swz(r, k)] * Wd2[k * 9 + o];
      out[nr * 9 + o] = a;
    }
  }
}

// ---------- launch ----------
extern "C" void kernel_launch(void* const* d_in, const int* in_sizes, int n_in,
                              void* d_out, int out_size, void* d_ws, size_t ws_size,
                              hipStream_t stream) {
  (void)in_sizes;
  (void)n_in;
  (void)out_size;
  (void)ws_size;
  const float* x = (const float*)d_in[0];
  const float* coords = (const float*)d_in[1];
  const int* ei = (const int*)d_in[2];
  const float* W_ne1 = (const float*)d_in[3];
  const float* b_ne1 = (const float*)d_in[4];
  const float* W_ne2 = (const float*)d_in[5];
  const float* b_ne2 = (const float*)d_in[6];
  const float* W_ee1 = (const float*)d_in[7];
  const float* b_ee1 = (const float*)d_in[8];
  const float* W_ee2 = (const float*)d_in[9];
  const float* b_ee2 = (const float*)d_in[10];
  const float* We1 = (const float*)d_in[11];
  const float* be1 = (const float*)d_in[12];
  const float* We2 = (const float*)d_in[13];
  const float* be2 = (const float*)d_in[14];
  const float* Wn1 = (const float*)d_in[15];
  const float* bn1 = (const float*)d_in[16];
  const float* Wn2 = (const float*)d_in[17];
  const float* bn2 = (const float*)d_in[18];
  const float* ln_g = (const float*)d_in[19];
  const float* ln_b = (const float*)d_in[20];
  const float* Wd1 = (const float*)d_in[21];
  const float* bd1 = (const float*)d_in[22];
  const float* Wd2 = (const float*)d_in[23];
  const float* bd2 = (const float*)d_in[24];
  float* out = (float*)d_out;

  char* ws = (char*)d_ws;
  size_t off = 0;
  auto alloc = [&](size_t bytes) -> void* {
    void* p = ws + off;
    off = (off + bytes + 255) & ~(size_t)255;
    return p;
  };
  float* h32 = (float*)alloc((size_t)NN * HD * 4);
  f16* h16 = (f16*)alloc((size_t)NN * HD * 2);
  f16* Pd = (f16*)alloc((size_t)NN * HD * 2);
  f16* Ps = (f16*)alloc((size_t)NN * HD * 2);
  float* agg = (float*)alloc((size_t)NN * HD * 4);
  f16* efS = (f16*)alloc((size_t)NE * 8 * 2);
  int* srcS = (int*)alloc((size_t)NE * 4);
  int* dstS = (int*)alloc((size_t)NE * 4);
  int* count = (int*)alloc((size_t)2 * NN * 4);  // count + cursor (contiguous)
  int* cursor = count + NN;
  int* startA = (int*)alloc((size_t)(NN + 1) * 4);
  f16* wt_ne2 = (f16*)alloc(128 * 128 * 2);
  f16* we1t = (f16*)alloc((size_t)6 * 128 * 384 * 2);
  f16* wn1t = (f16*)alloc((size_t)6 * 128 * 256 * 2);
  f16* wn2t = (f16*)alloc((size_t)6 * 128 * 128 * 2);
  f16* wd1t = (f16*)alloc(128 * 128 * 2);
  f16* mt = (f16*)alloc((size_t)6 * 128 * 128 * 2);
  float* cvec = (float*)alloc((size_t)6 * 128 * 4);
  f16* wzt = (f16*)alloc((size_t)6 * 128 * 128 * 2);
  float* bvv = (float*)alloc((size_t)6 * 128 * 4);
  f16* w1e8 = (f16*)alloc(128 * 8 * 2);

  TJobs jobs;
  int nj = 0;
  jobs.j[nj++] = {W_ne2, wt_ne2, 128, 128};
  for (int l = 0; l < 6; ++l)
    jobs.j[nj++] = {We1 + (size_t)l * 384 * 128, we1t + (size_t)l * 128 * 384, 384, 128};
  for (int l = 0; l < 6; ++l)
    jobs.j[nj++] = {Wn1 + (size_t)l * 256 * 128, wn1t + (size_t)l * 128 * 256, 256, 128};
  for (int l = 0; l < 6; ++l)
    jobs.j[nj++] = {Wn2 + (size_t)l * 128 * 128, wn2t + (size_t)l * 128 * 128, 128, 128};
  jobs.j[nj++] = {Wd1, wd1t, 128, 128};

  const int* srcI = ei;       // edge_index[0]
  const int* dstI = ei + NE;  // edge_index[1]
  const int EB = (NE + 255) / 256;
  const int NT = (NN + 63) / 64;
  const int ET = (NE + 63) / 64;

  k_prep<<<nj * 4, 256, 0, stream>>>(jobs);
  k_prep_E<<<1, 128, 0, stream>>>(W_ee1, w1e8);
  k_prep_M<<<6 * 128, 128, 0, stream>>>(W_ee2, b_ee2, We1, mt, cvec);
  k_prep_Z<<<6 * 128, 128, 0, stream>>>(We2, be2, Wn1, wzt, bvv);
  hipMemsetAsync(count, 0, (size_t)2 * NN * 4, stream);
  hipMemsetAsync(agg, 0, (size_t)NN * HD * 4, stream);
  k_hist<<<EB, 256, 0, stream>>>(dstI, count);
  k_scan<<<1, 1024, 0, stream>>>(count, startA);
  k_scatter<<<EB, 256, 0, stream>>>(srcI, dstI, coords, startA, cursor, srcS, dstS, efS);
  k_enc_node<<<NT, 256, 0, stream>>>(x, W_ne1, b_ne1, wt_ne2, b_ne2, we1t, be1, cvec,
                                     h32, h16, Pd, Ps);

  for (int l = 0; l < 6; ++l) {
    int ln = (l + 1 < 6) ? (l + 1) : 0;  // dummy weights for last layer (doPP=0)
    k_edge<<<ET, 512, 0, stream>>>(efS, srcS, dstS, Pd, Ps, w1e8, b_ee1,
                                   mt + (size_t)l * 128 * 128, agg, ET);
    k_node<<<NT, 512, 0, stream>>>(
        h16, agg, startA, wn1t + (size_t)l * 128 * 256, bn1 + l * 128,
        wzt + (size_t)l * 128 * 128, bvv + l * 128, wn2t + (size_t)l * 128 * 128,
        bn2 + l * 128, ln_g + l * 128, ln_b + l * 128,
        we1t + (size_t)ln * 128 * 384, be1 + ln * 128, cvec + ln * 128, h32, h16,
        Pd, Ps, (l + 1 < 6) ? 1 : 0);
  }
  k_dec<<<NT, 256, 0, stream>>>(h16, wd1t, bd1, Wd2, bd2, out);
}

// Round 6
// 1339.636 us; speedup vs baseline: 1.0886x; 1.0886x over previous
//
#include <hip/hip_runtime.h>

#define NN 50000
#define NE 500000
#define HD 128

typedef _Float16 f16;
typedef _Float16 f16x8 __attribute__((ext_vector_type(8)));
typedef _Float16 f16x4 __attribute__((ext_vector_type(4)));
typedef float f32x4 __attribute__((ext_vector_type(4)));

// ---------- helpers ----------

// XOR-swizzled LDS index for a [rows][128] f16 tile (16B-chunk swizzle, no pad).
__device__ __forceinline__ int swz(int r, int c) {
  return r * HD + ((((c >> 3) ^ r) & 15) << 3) + (c & 7);
}

__device__ __forceinline__ float fast_silu(float x) {
  return x * __builtin_amdgcn_rcpf(1.0f + __expf(-x));
}

// One wave computes a 32x64 sub-tile of D(64x128) = A(64x128) @ W^T. (256-thr blocks)
__device__ __forceinline__ void gemm_wave_g(const f16* A, const f16* __restrict__ Wg,
                                            int wstride, int rowBase, int colBase,
                                            f32x4 acc[2][4]) {
  const int lane = (int)threadIdx.x & 63;
  const int m = lane & 15;
  const int q = lane >> 4;
#pragma unroll
  for (int kc = 0; kc < 4; ++kc) {
    const int pc = (((kc * 4 + q) ^ m) & 15) << 3;  // swizzled A k-chunk offset
    const int gk = (kc * 4 + q) << 3;               // linear k offset for global W
    f16x8 a0 = *(const f16x8*)(A + (rowBase + m) * HD + pc);
    f16x8 a1 = *(const f16x8*)(A + (rowBase + 16 + m) * HD + pc);
#pragma unroll
    for (int ct = 0; ct < 4; ++ct) {
      f16x8 b = *(const f16x8*)(Wg + (colBase + ct * 16 + m) * wstride + gk);
      acc[0][ct] = __builtin_amdgcn_mfma_f32_16x16x32_f16(a0, b, acc[0][ct], 0, 0, 0);
      acc[1][ct] = __builtin_amdgcn_mfma_f32_16x16x32_f16(a1, b, acc[1][ct], 0, 0, 0);
    }
  }
}

// One wave computes a 32x32 sub-tile (512-thread blocks, 8 waves over 64x128).
__device__ __forceinline__ void gemm_wave_g2(const f16* A, const f16* __restrict__ Wg,
                                             int wstride, int rowBase, int colBase,
                                             f32x4 acc[2][2]) {
  const int lane = (int)threadIdx.x & 63;
  const int m = lane & 15;
  const int q = lane >> 4;
#pragma unroll
  for (int kc = 0; kc < 4; ++kc) {
    const int pc = (((kc * 4 + q) ^ m) & 15) << 3;
    const int gk = (kc * 4 + q) << 3;
    f16x8 a0 = *(const f16x8*)(A + (rowBase + m) * HD + pc);
    f16x8 a1 = *(const f16x8*)(A + (rowBase + 16 + m) * HD + pc);
#pragma unroll
    for (int ct = 0; ct < 2; ++ct) {
      f16x8 b = *(const f16x8*)(Wg + (colBase + ct * 16 + m) * wstride + gk);
      acc[0][ct] = __builtin_amdgcn_mfma_f32_16x16x32_f16(a0, b, acc[0][ct], 0, 0, 0);
      acc[1][ct] = __builtin_amdgcn_mfma_f32_16x16x32_f16(a1, b, acc[1][ct], 0, 0, 0);
    }
  }
}

#define ZACC(acc)                                        \
  {                                                      \
    _Pragma("unroll") for (int zi = 0; zi < 2; ++zi)     \
        _Pragma("unroll") for (int zj = 0; zj < 4; ++zj) \
            acc[zi][zj] = (f32x4){0.f, 0.f, 0.f, 0.f};   \
  }

#define ZACC2(acc)                                       \
  {                                                      \
    _Pragma("unroll") for (int zi = 0; zi < 2; ++zi)     \
        _Pragma("unroll") for (int zj = 0; zj < 2; ++zj) \
            acc[zi][zj] = (f32x4){0.f, 0.f, 0.f, 0.f};   \
  }

// cooperative 64x128 f16 tile: global(row-major, stride HD) <-> swizzled LDS
template <int TPB>
__device__ __forceinline__ void stage_rows64(const f16* __restrict__ g, long r0,
                                             long lim, f16* lds) {
#pragma unroll
  for (int it = 0; it < 1024 / TPB; ++it) {
    int idx = it * TPB + (int)threadIdx.x;
    int r = idx >> 4, ck = idx & 15;
    f16x8 v = {};
    if (r0 + r < lim) v = *(const f16x8*)(g + (r0 + r) * HD + ck * 8);
    *(f16x8*)(lds + r * HD + (((ck ^ r) & 15) << 3)) = v;
  }
}
template <int TPB>
__device__ __forceinline__ void store_rows64(const f16* lds, f16* __restrict__ g,
                                             long r0, long lim) {
#pragma unroll
  for (int it = 0; it < 1024 / TPB; ++it) {
    int idx = it * TPB + (int)threadIdx.x;
    int r = idx >> 4, ck = idx & 15;
    if (r0 + r < lim)
      *(f16x8*)(g + (r0 + r) * HD + ck * 8) =
          *(const f16x8*)(lds + r * HD + (((ck ^ r) & 15) << 3));
  }
}

// ---------- weight prep (fp32 (in,out) -> f16 [out][in]) ----------
struct TJob {
  const float* src;
  f16* dst;
  int idim;
  int odim;
};
struct TJobs {
  TJob j[27];
};

__global__ __launch_bounds__(256) void k_prep(TJobs jobs) {
  int job = blockIdx.x >> 2;
  int part = blockIdx.x & 3;
  TJob J = jobs.j[job];
  int total = J.idim * J.odim;
  for (int idx = part * 256 + (int)threadIdx.x; idx < total; idx += 1024) {
    int o = idx / J.idim;
    int i = idx - o * J.idim;
    J.dst[idx] = (f16)J.src[(long)i * J.odim + o];
  }
}

// Wee1 (4x128 f32) -> f16 [128][8] zero-padded to K=8
__global__ __launch_bounds__(128) void k_prep_E(const float* __restrict__ W,
                                                f16* __restrict__ W8) {
  int t = threadIdx.x;
#pragma unroll
  for (int i = 0; i < 8; ++i) W8[t * 8 + i] = (i < 4) ? (f16)W[i * 128 + t] : (f16)0.f;
}

// ---------- folded edge-encoder weights ----------
// Mt[l][o][h] = sum_e Wee2[h][e] * We1[l][2H+e][o]   (f16, [out][in] layout)
// cv[l][o]   = sum_e b2[e]      * We1[l][2H+e][o]   (f32)
__global__ __launch_bounds__(128) void k_prep_M(const float* __restrict__ Wee2,
                                                const float* __restrict__ b2,
                                                const float* __restrict__ We1,
                                                f16* __restrict__ Mt,
                                                float* __restrict__ cv) {
  __shared__ float col[128];
  int l = blockIdx.x >> 7, o = blockIdx.x & 127;
  int t = threadIdx.x;
  col[t] = We1[((size_t)l * 384 + 256 + t) * 128 + o];
  __syncthreads();
  float s = 0.f;
#pragma unroll 8
  for (int e = 0; e < 128; ++e) s += Wee2[t * 128 + e] * col[e];
  Mt[((size_t)l * 128 + o) * 128 + t] = (f16)s;
  if (t == 0) {
    float c = 0.f;
    for (int e = 0; e < 128; ++e) c += b2[e] * col[e];
    cv[l * 128 + o] = c;
  }
}

// ---------- folded aggregation weights ----------
// WZ[l] = We2[l] @ Wn1_agg[l]  (agg rows 128..255 of Wn1), stored f16 [out][in]
// bv[l][o] = sum_j be2[l][j] * Wn1[l][128+j][o]  (f32)
__global__ __launch_bounds__(128) void k_prep_Z(const float* __restrict__ We2,
                                                const float* __restrict__ be2,
                                                const float* __restrict__ Wn1,
                                                f16* __restrict__ WZt,
                                                float* __restrict__ bve) {
  __shared__ float col[128];
  int l = blockIdx.x >> 7, o = blockIdx.x & 127;
  int t = threadIdx.x;
  col[t] = Wn1[((size_t)l * 256 + 128 + t) * 128 + o];
  __syncthreads();
  float s = 0.f;
#pragma unroll 8
  for (int j = 0; j < 128; ++j) s += We2[(size_t)l * 128 * 128 + t * 128 + j] * col[j];
  WZt[((size_t)l * 128 + o) * 128 + t] = (f16)s;
  if (t == 0) {
    float c = 0.f;
    for (int j = 0; j < 128; ++j) c += be2[l * 128 + j] * col[j];
    bve[l * 128 + o] = c;
  }
}

// ---------- counting sort by dst ----------
__global__ __launch_bounds__(256) void k_hist(const int* __restrict__ dst,
                                              int* __restrict__ count) {
  int e = blockIdx.x * 256 + threadIdx.x;
  if (e < NE) atomicAdd(&count[dst[e]], 1);
}

__global__ __launch_bounds__(1024) void k_scan(const int* __restrict__ count,
                                               int* __restrict__ startA) {
  __shared__ int lds[1024];
  const int CH = 49;  // 49*1024 >= NN
  int t = threadIdx.x;
  int b = t * CH;
  int e = b + CH < NN ? b + CH : NN;
  int s = 0;
  for (int i = b; i < e; ++i) s += count[i];
  lds[t] = s;
  __syncthreads();
  for (int off = 1; off < 1024; off <<= 1) {
    int v = (t >= off) ? lds[t - off] : 0;
    __syncthreads();
    lds[t] += v;
    __syncthreads();
  }
  int run = lds[t] - s;  // exclusive prefix of this chunk
  for (int i = b; i < e; ++i) {
    startA[i] = run;
    run += count[i];
  }
  if (t == 0) startA[NN] = NE;
}

__global__ __launch_bounds__(256) void k_scatter(const int* __restrict__ src,
                                                 const int* __restrict__ dst,
                                                 const float* __restrict__ coords,
                                                 const int* __restrict__ startA,
                                                 int* __restrict__ cursor,
                                                 int* __restrict__ srcS,
                                                 int* __restrict__ dstS,
                                                 f16* __restrict__ efS) {
  int e = blockIdx.x * 256 + threadIdx.x;
  if (e >= NE) return;
  int s = src[e];
  int n = dst[e];
  int pos = startA[n] + atomicAdd(&cursor[n], 1);
  srcS[pos] = s;
  dstS[pos] = n;
  float rx = coords[n * 3] - coords[s * 3];
  float ry = coords[n * 3 + 1] - coords[s * 3 + 1];
  float rz = coords[n * 3 + 2] - coords[s * 3 + 2];
  float nr = sqrtf(rx * rx + ry * ry + rz * rz);
  f16x8 v = {};
  v[0] = (f16)rx;
  v[1] = (f16)ry;
  v[2] = (f16)rz;
  v[3] = (f16)nr;
  *(f16x8*)(efS + (long)pos * 8) = v;
}

// ---------- node encoder: h = silu(x@Wne1+b)@Wne2+b ; also layer-0 Pd/Ps ----------
__global__ __launch_bounds__(256, 4) void k_enc_node(
    const float* __restrict__ x, const float* __restrict__ W1,
    const float* __restrict__ b1, const f16* __restrict__ W2t,
    const float* __restrict__ b2, const f16* __restrict__ We1t0,
    const float* __restrict__ be10, const float* __restrict__ cvec0,
    float* __restrict__ h32, f16* __restrict__ h16, f16* __restrict__ Pd,
    f16* __restrict__ Ps) {
  __shared__ __align__(16) f16 lds_A[64 * HD];
  __shared__ __align__(16) f16 lds_O[64 * HD];
  float* lds_x = (float*)lds_O;  // alias O
  long r0 = (long)blockIdx.x * 64;
  int t = threadIdx.x;
  int wv = t >> 6, lane = t & 63, nn = lane & 15, q = lane >> 4;
  int rowBase = (wv >> 1) * 32, colBase = (wv & 1) * 64;

  if (t < 192) {
    long i = r0 * 3 + t;
    lds_x[t] = (i < (long)NN * 3) ? x[i] : 0.f;
  }
  __syncthreads();

  for (int it = 0; it < 32; ++it) {
    int idx = it * 256 + t;
    int r = idx >> 7, c = idx & 127;
    float a = b1[c];
    a += lds_x[r * 3 + 0] * W1[0 * HD + c];
    a += lds_x[r * 3 + 1] * W1[1 * HD + c];
    a += lds_x[r * 3 + 2] * W1[2 * HD + c];
    lds_A[swz(r, c)] = (f16)fast_silu(a);
  }
  __syncthreads();

  f32x4 acc[2][4];
  ZACC(acc);
  gemm_wave_g(lds_A, W2t, HD, rowBase, colBase, acc);
#pragma unroll
  for (int rt = 0; rt < 2; ++rt)
#pragma unroll
    for (int ct = 0; ct < 4; ++ct)
#pragma unroll
      for (int rg = 0; rg < 4; ++rg) {
        int row = rowBase + rt * 16 + q * 4 + rg;
        int col = colBase + ct * 16 + nn;
        float v = acc[rt][ct][rg] + b2[col];
        long nr = r0 + row;
        if (nr < NN) h32[nr * HD + col] = v;
        lds_O[swz(row, col)] = (f16)v;
      }
  __syncthreads();  // lds_O (h) complete; lds_A free (all waves past GEMM)
  store_rows64<256>(lds_O, h16, r0, NN);

  // layer-0 Pd = h@W_d + be1 + cv -> via lds_A
  ZACC(acc);
  gemm_wave_g(lds_O, We1t0, 384, rowBase, colBase, acc);
#pragma unroll
  for (int rt = 0; rt < 2; ++rt)
#pragma unroll
    for (int ct = 0; ct < 4; ++ct)
#pragma unroll
      for (int rg = 0; rg < 4; ++rg) {
        int row = rowBase + rt * 16 + q * 4 + rg;
        int col = colBase + ct * 16 + nn;
        lds_A[swz(row, col)] = (f16)(acc[rt][ct][rg] + be10[col] + cvec0[col]);
      }
  __syncthreads();
  store_rows64<256>(lds_A, Pd, r0, NN);

  // layer-0 Ps = h@W_s
  ZACC(acc);
  gemm_wave_g(lds_O, We1t0 + 128, 384, rowBase, colBase, acc);
  __syncthreads();  // all waves done store-reading lds_A (Pd)
#pragma unroll
  for (int rt = 0; rt < 2; ++rt)
#pragma unroll
    for (int ct = 0; ct < 4; ++ct)
#pragma unroll
      for (int rg = 0; rg < 4; ++rg) {
        int row = rowBase + rt * 16 + q * 4 + rg;
        int col = colBase + ct * 16 + nn;
        lds_A[swz(row, col)] = (f16)acc[rt][ct][rg];
      }
  __syncthreads();
  store_rows64<256>(lds_A, Ps, r0, NN);
}

// ---------- per-layer edge kernel (512 thr, 8 waves) ----------
// z = silu(silu2@Mt + Pd[dst]+Ps[src]); silu2 computed via K=8-packed MFMA.
// Segmented z-sum: plain store for quarter-interior runs, atomic at boundaries.
__global__ __launch_bounds__(512, 8) void k_edge(
    const f16* __restrict__ efS, const int* __restrict__ srcS,
    const int* __restrict__ dstS, const f16* __restrict__ Pd,
    const f16* __restrict__ Ps, const f16* __restrict__ W1e8,
    const float* __restrict__ b1, const f16* __restrict__ Mt,
    float* __restrict__ zs, int nwg) {
  __shared__ __align__(16) f16 lds_A[64 * HD];  // silu2
  __shared__ __align__(16) f16 lds_P[64 * HD];  // pdps, then z
  __shared__ int dstL[64];
  // bijective XCD-chunked swizzle: consecutive logical blocks -> same XCD
  int orig = blockIdx.x;
  int xcd = orig & 7, loc = orig >> 3;
  int qq = nwg >> 3, rr = nwg & 7;
  int wg = (xcd < rr ? xcd * (qq + 1) : rr * (qq + 1) + (xcd - rr) * qq) + loc;
  long e0 = (long)wg * 64;
  int t = threadIdx.x;
  int lane = t & 63, nn = lane & 15, q = lane >> 4;
  int wv = t >> 6;
  int rowBase = (wv >> 2) * 32, colBase = (wv & 3) * 32;

  if (t < 64) {
    long e = e0 + t;
    dstL[t] = (e < NE) ? dstS[e] : -1;
  }

  // silu2 A/B fragments: only q==0 lanes carry k=0..7 (ef padded 4->8)
  f16x8 ea0 = {}, ea1 = {}, eb0 = {}, eb1 = {};
  if (q == 0) {
    long er0 = e0 + rowBase + nn;
    long er1 = er0 + 16;
    if (er0 < NE) ea0 = *(const f16x8*)(efS + er0 * 8);
    if (er1 < NE) ea1 = *(const f16x8*)(efS + er1 * 8);
    eb0 = *(const f16x8*)(W1e8 + (colBase + nn) * 8);
    eb1 = *(const f16x8*)(W1e8 + (colBase + 16 + nn) * 8);
  }
  f32x4 sacc[2][2];
  ZACC2(sacc);
  sacc[0][0] = __builtin_amdgcn_mfma_f32_16x16x32_f16(ea0, eb0, sacc[0][0], 0, 0, 0);
  sacc[1][0] = __builtin_amdgcn_mfma_f32_16x16x32_f16(ea1, eb0, sacc[1][0], 0, 0, 0);
  sacc[0][1] = __builtin_amdgcn_mfma_f32_16x16x32_f16(ea0, eb1, sacc[0][1], 0, 0, 0);
  sacc[1][1] = __builtin_amdgcn_mfma_f32_16x16x32_f16(ea1, eb1, sacc[1][1], 0, 0, 0);

  // pdps gathers -> registers (latency hidden under silu2 epilogue)
  int rr0 = t >> 4, rr1 = 32 + (t >> 4);
  int ck = t & 15;
  f16x8 pa0 = {}, pb0 = {}, pa1 = {}, pb1 = {};
  {
    long e = e0 + rr0;
    if (e < NE) {
      int d = dstS[e], s = srcS[e];
      pa0 = *(const f16x8*)(Pd + (long)d * HD + ck * 8);
      pb0 = *(const f16x8*)(Ps + (long)s * HD + ck * 8);
    }
  }
  {
    long e = e0 + rr1;
    if (e < NE) {
      int d = dstS[e], s = srcS[e];
      pa1 = *(const f16x8*)(Pd + (long)d * HD + ck * 8);
      pb1 = *(const f16x8*)(Ps + (long)s * HD + ck * 8);
    }
  }

  // silu2 epilogue -> lds_A (swizzled, f16)
  {
    float b1v0 = b1[colBase + nn], b1v1 = b1[colBase + 16 + nn];
#pragma unroll
    for (int rt = 0; rt < 2; ++rt)
#pragma unroll
      for (int ct = 0; ct < 2; ++ct) {
        float bb = ct ? b1v1 : b1v0;
        int col = colBase + ct * 16 + nn;
#pragma unroll
        for (int rg = 0; rg < 4; ++rg) {
          int row = rowBase + rt * 16 + q * 4 + rg;
          lds_A[swz(row, col)] = (f16)fast_silu(sacc[rt][ct][rg] + bb);
        }
      }
  }
  // pdps -> lds_P
  {
    f16x8 v = pa0 + pb0;
    *(f16x8*)(lds_P + rr0 * HD + (((ck ^ rr0) & 15) << 3)) = v;
  }
  {
    f16x8 v = pa1 + pb1;
    *(f16x8*)(lds_P + rr1 * HD + (((ck ^ rr1) & 15) << 3)) = v;
  }
  __syncthreads();

  f32x4 acc[2][2];
  ZACC2(acc);
  gemm_wave_g2(lds_A, Mt, HD, rowBase, colBase, acc);  // silu2 @ Mt[l]

  // z = silu(acc + pdps) in-place into OWN 32x32 region of lds_P (cv in Pd)
#pragma unroll
  for (int rt = 0; rt < 2; ++rt)
#pragma unroll
    for (int ct = 0; ct < 2; ++ct)
#pragma unroll
      for (int rg = 0; rg < 4; ++rg) {
        int row = rowBase + rt * 16 + q * 4 + rg;
        int col = colBase + ct * 16 + nn;
        float v = acc[rt][ct][rg] + (float)lds_P[swz(row, col)];
        lds_P[swz(row, col)] = (f16)fast_silu(v);
      }
  __syncthreads();

  // segmented z-sum over sorted dst runs; quarter-interior runs: plain store
  {
    int c = t & 127, qt = t >> 7;
    int rb = qt * 16;
    int dfirst = dstL[rb], dlast = dstL[rb + 15];
    int prev = dfirst;
    float sum = 0.f;
    for (int r = rb; r < rb + 16; ++r) {
      int d = dstL[r];
      if (d != prev) {
        if (prev >= 0) {
          if (prev == dfirst || prev == dlast)
            atomicAdd(&zs[(long)prev * HD + c], sum);
          else
            zs[(long)prev * HD + c] = sum;  // sole writer for interior run
        }
        sum = 0.f;
        prev = d;
      }
      sum += (float)lds_P[swz(r, c)];
    }
    if (prev >= 0) atomicAdd(&zs[(long)prev * HD + c], sum);
  }
}

// ---------- per-layer node kernel (256 thr, round-4 codegen): upd MLP +
// residual + LayerNorm, then Pd/Ps for the NEXT layer from the y tile. ----------
__global__ __launch_bounds__(256, 4) void k_node(
    const f16* __restrict__ h16in, float* __restrict__ zsum,
    const int* __restrict__ startA, const f16* __restrict__ Wn1t,
    const float* __restrict__ bn1, const f16* __restrict__ WZt,
    const float* __restrict__ bve, const f16* __restrict__ Wn2t,
    const float* __restrict__ bn2, const float* __restrict__ lg,
    const float* __restrict__ lb, const f16* __restrict__ We1tN,
    const float* __restrict__ be1N, const float* __restrict__ cvecN,
    float* __restrict__ h32, f16* __restrict__ h16out, f16* __restrict__ Pd,
    f16* __restrict__ Ps, int doPP) {
  __shared__ __align__(16) f16 lds_A[64 * HD];  // h, then y
  __shared__ __align__(16) f16 lds_B[64 * HD];  // zbar, then z, then PP staging
  __shared__ float lds_s[512];
  __shared__ float degf[64];
  long r0 = (long)blockIdx.x * 64;
  int t = threadIdx.x;
  int wv = t >> 6, lane = t & 63, nn = lane & 15, q = lane >> 4;
  int rowBase = (wv >> 1) * 32, colBase = (wv & 1) * 64;

  stage_rows64<256>(h16in, r0, NN, lds_A);
  // zbar = zsum / max(deg,1) -> f16 ; zero zsum for next layer
#pragma unroll
  for (int it = 0; it < 8; ++it) {
    int idx = it * 256 + t;
    int r = idx >> 5, c4 = (idx & 31) * 4;
    long nr = r0 + r;
    f16x4 v = {};
    if (nr < NN) {
      float deg = (float)(startA[nr + 1] - startA[nr]);
      float inv = __builtin_amdgcn_rcpf(fmaxf(deg, 1.0f));
      float4 a = *(const float4*)(zsum + nr * HD + c4);
      *(float4*)(zsum + nr * HD + c4) = (float4){0.f, 0.f, 0.f, 0.f};
      v[0] = (f16)(a.x * inv);
      v[1] = (f16)(a.y * inv);
      v[2] = (f16)(a.z * inv);
      v[3] = (f16)(a.w * inv);
      if (c4 == 0) degf[r] = deg > 0.f ? 1.f : 0.f;
    } else if (c4 == 0) {
      degf[r] = 0.f;
    }
    *(f16x4*)(lds_B + swz(r, c4)) = v;
  }
  __syncthreads();

  f32x4 acc[2][4];
  ZACC(acc);
  gemm_wave_g(lds_A, Wn1t, 256, rowBase, colBase, acc);  // h part
  gemm_wave_g(lds_B, WZt, HD, rowBase, colBase, acc);    // zbar part (We2 folded)
  __syncthreads();  // all waves done reading lds_B before z overwrite

  // z = silu(acc + bn1 + [deg>0]*bv) -> lds_B
#pragma unroll
  for (int rt = 0; rt < 2; ++rt)
#pragma unroll
    for (int ct = 0; ct < 4; ++ct)
#pragma unroll
      for (int rg = 0; rg < 4; ++rg) {
        int row = rowBase + rt * 16 + q * 4 + rg;
        int col = colBase + ct * 16 + nn;
        lds_B[swz(row, col)] =
            (f16)fast_silu(acc[rt][ct][rg] + bn1[col] + degf[row] * bve[col]);
      }
  __syncthreads();

  ZACC(acc);
  gemm_wave_g(lds_B, Wn2t, HD, rowBase, colBase, acc);

  // residual + LN stats
  float vv[2][4][4];
  float s1[8], s2[8];
#pragma unroll
  for (int i = 0; i < 8; ++i) {
    s1[i] = 0.f;
    s2[i] = 0.f;
  }
#pragma unroll
  for (int rt = 0; rt < 2; ++rt)
#pragma unroll
    for (int ct = 0; ct < 4; ++ct)
#pragma unroll
      for (int rg = 0; rg < 4; ++rg) {
        int row = rowBase + rt * 16 + q * 4 + rg;
        int col = colBase + ct * 16 + nn;
        long nr = r0 + row;
        float hv = (nr < NN) ? h32[nr * HD + col] : 0.f;
        float v = acc[rt][ct][rg] + bn2[col] + hv;
        vv[rt][ct][rg] = v;
        s1[rt * 4 + rg] += v;
        s2[rt * 4 + rg] += v * v;
      }
#pragma unroll
  for (int msk = 1; msk <= 8; msk <<= 1) {
#pragma unroll
    for (int i = 0; i < 8; ++i) {
      s1[i] += __shfl_xor(s1[i], msk, 64);
      s2[i] += __shfl_xor(s2[i], msk, 64);
    }
  }
  int ch = wv & 1;
  if (nn == 0) {
#pragma unroll
    for (int rt = 0; rt < 2; ++rt)
#pragma unroll
      for (int rg = 0; rg < 4; ++rg) {
        int row = rowBase + rt * 16 + q * 4 + rg;
        lds_s[row * 2 + ch] = s1[rt * 4 + rg];
        lds_s[256 + row * 2 + ch] = s2[rt * 4 + rg];
      }
  }
  __syncthreads();
#pragma unroll
  for (int rt = 0; rt < 2; ++rt)
#pragma unroll
    for (int ct = 0; ct < 4; ++ct)
#pragma unroll
      for (int rg = 0; rg < 4; ++rg) {
        int row = rowBase + rt * 16 + q * 4 + rg;
        int col = colBase + ct * 16 + nn;
        long nr = r0 + row;
        float S1 = lds_s[row * 2] + lds_s[row * 2 + 1];
        float S2 = lds_s[256 + row * 2] + lds_s[256 + row * 2 + 1];
        float mean = S1 * (1.0f / 128.0f);
        float var = S2 * (1.0f / 128.0f) - mean * mean;
        float rstd = rsqrtf(var + 1e-5f);
        float y = (vv[rt][ct][rg] - mean) * rstd * lg[col] + lb[col];
        if (nr < NN) h32[nr * HD + col] = y;
        lds_A[swz(row, col)] = (f16)y;
      }
  __syncthreads();  // y tile complete in lds_A
  store_rows64<256>(lds_A, h16out, r0, NN);

  if (doPP) {
    // Pd(next) = y@W_d + be1 + cv
    ZACC(acc);
    gemm_wave_g(lds_A, We1tN, 384, rowBase, colBase, acc);
#pragma unroll
    for (int rt = 0; rt < 2; ++rt)
#pragma unroll
      for (int ct = 0; ct < 4; ++ct)
#pragma unroll
        for (int rg = 0; rg < 4; ++rg) {
          int row = rowBase + rt * 16 + q * 4 + rg;
          int col = colBase + ct * 16 + nn;
          lds_B[swz(row, col)] = (f16)(acc[rt][ct][rg] + be1N[col] + cvecN[col]);
        }
    __syncthreads();
    store_rows64<256>(lds_B, Pd, r0, NN);

    // Ps(next) = y@W_s
    ZACC(acc);
    gemm_wave_g(lds_A, We1tN + 128, 384, rowBase, colBase, acc);
    __syncthreads();  // all waves done store-reading lds_B (Pd)
#pragma unroll
    for (int rt = 0; rt < 2; ++rt)
#pragma unroll
      for (int ct = 0; ct < 4; ++ct)
#pragma unroll
        for (int rg = 0; rg < 4; ++rg) {
          int row = rowBase + rt * 16 + q * 4 + rg;
          int col = colBase + ct * 16 + nn;
          lds_B[swz(row, col)] = (f16)acc[rt][ct][rg];
        }
    __syncthreads();
    store_rows64<256>(lds_B, Ps, r0, NN);
  }
}

// ---------- decoder ----------
__global__ __launch_bounds__(256, 4) void k_dec(
    const f16* __restrict__ h16, const f16* __restrict__ Wd1t,
    const float* __restrict__ bd1, const float* __restrict__ Wd2,
    const float* __restrict__ bd2, float* __restrict__ out) {
  __shared__ __align__(16) f16 lds_A[64 * HD];
  __shared__ __align__(16) f16 lds_O[64 * HD];
  long r0 = (long)blockIdx.x * 64;
  int t = threadIdx.x;
  int wv = t >> 6, lane = t & 63, nn = lane & 15, q = lane >> 4;
  int rowBase = (wv >> 1) * 32, colBase = (wv & 1) * 64;

  stage_rows64<256>(h16, r0, NN, lds_A);
  __syncthreads();

  f32x4 acc[2][4];
  ZACC(acc);
  gemm_wave_g(lds_A, Wd1t, HD, rowBase, colBase, acc);
#pragma unroll
  for (int rt = 0; rt < 2; ++rt)
#pragma unroll
    for (int ct = 0; ct < 4; ++ct)
#pragma unroll
      for (int rg = 0; rg < 4; ++rg) {
        int row = rowBase + rt * 16 + q * 4 + rg;
        int col = colBase + ct * 16 + nn;
        lds_O[swz(row, col)] = (f16)fast_silu(acc[rt][ct][rg] + bd1[col]);
      }
  __syncthreads();

  for (int idx = t; idx < 64 * 9; idx += 256) {
    int r = idx / 9;
    int o = idx - r * 9;
    long nr = r0 + r;
    if (nr < NN) {
      float a = bd2[o];
      for (int k = 0; k < 128; ++k) a += (float)lds_O[swz(r, k)] * Wd2[k * 9 + o];
      out[nr * 9 + o] = a;
    }
  }
}

// ---------- launch ----------
extern "C" void kernel_launch(void* const* d_in, const int* in_sizes, int n_in,
                              void* d_out, int out_size, void* d_ws, size_t ws_size,
                              hipStream_t stream) {
  (void)in_sizes;
  (void)n_in;
  (void)out_size;
  (void)ws_size;
  const float* x = (const float*)d_in[0];
  const float* coords = (const float*)d_in[1];
  const int* ei = (const int*)d_in[2];
  const float* W_ne1 = (const float*)d_in[3];
  const float* b_ne1 = (const float*)d_in[4];
  const float* W_ne2 = (const float*)d_in[5];
  const float* b_ne2 = (const float*)d_in[6];
  const float* W_ee1 = (const float*)d_in[7];
  const float* b_ee1 = (const float*)d_in[8];
  const float* W_ee2 = (const float*)d_in[9];
  const float* b_ee2 = (const float*)d_in[10];
  const float* We1 = (const float*)d_in[11];
  const float* be1 = (const float*)d_in[12];
  const float* We2 = (const float*)d_in[13];
  const float* be2 = (const float*)d_in[14];
  const float* Wn1 = (const float*)d_in[15];
  const float* bn1 = (const float*)d_in[16];
  const float* Wn2 = (const float*)d_in[17];
  const float* bn2 = (const float*)d_in[18];
  const float* ln_g = (const float*)d_in[19];
  const float* ln_b = (const float*)d_in[20];
  const float* Wd1 = (const float*)d_in[21];
  const float* bd1 = (const float*)d_in[22];
  const float* Wd2 = (const float*)d_in[23];
  const float* bd2 = (const float*)d_in[24];
  float* out = (float*)d_out;

  char* ws = (char*)d_ws;
  size_t off = 0;
  auto alloc = [&](size_t bytes) -> void* {
    void* p = ws + off;
    off = (off + bytes + 255) & ~(size_t)255;
    return p;
  };
  float* h32 = (float*)alloc((size_t)NN * HD * 4);
  f16* h16 = (f16*)alloc((size_t)NN * HD * 2);
  f16* Pd = (f16*)alloc((size_t)NN * HD * 2);
  f16* Ps = (f16*)alloc((size_t)NN * HD * 2);
  float* agg = (float*)alloc((size_t)NN * HD * 4);
  f16* efS = (f16*)alloc((size_t)NE * 8 * 2);
  int* srcS = (int*)alloc((size_t)NE * 4);
  int* dstS = (int*)alloc((size_t)NE * 4);
  int* count = (int*)alloc((size_t)2 * NN * 4);  // count + cursor (contiguous)
  int* cursor = count + NN;
  int* startA = (int*)alloc((size_t)(NN + 1) * 4);
  f16* wt_ne2 = (f16*)alloc(128 * 128 * 2);
  f16* we1t = (f16*)alloc((size_t)6 * 128 * 384 * 2);
  f16* wn1t = (f16*)alloc((size_t)6 * 128 * 256 * 2);
  f16* wn2t = (f16*)alloc((size_t)6 * 128 * 128 * 2);
  f16* wd1t = (f16*)alloc(128 * 128 * 2);
  f16* mt = (f16*)alloc((size_t)6 * 128 * 128 * 2);
  float* cvec = (float*)alloc((size_t)6 * 128 * 4);
  f16* wzt = (f16*)alloc((size_t)6 * 128 * 128 * 2);
  float* bvv = (float*)alloc((size_t)6 * 128 * 4);
  f16* w1e8 = (f16*)alloc(128 * 8 * 2);

  TJobs jobs;
  int nj = 0;
  jobs.j[nj++] = {W_ne2, wt_ne2, 128, 128};
  for (int l = 0; l < 6; ++l)
    jobs.j[nj++] = {We1 + (size_t)l * 384 * 128, we1t + (size_t)l * 128 * 384, 384, 128};
  for (int l = 0; l < 6; ++l)
    jobs.j[nj++] = {Wn1 + (size_t)l * 256 * 128, wn1t + (size_t)l * 128 * 256, 256, 128};
  for (int l = 0; l < 6; ++l)
    jobs.j[nj++] = {Wn2 + (size_t)l * 128 * 128, wn2t + (size_t)l * 128 * 128, 128, 128};
  jobs.j[nj++] = {Wd1, wd1t, 128, 128};

  const int* srcI = ei;       // edge_index[0]
  const int* dstI = ei + NE;  // edge_index[1]
  const int EB = (NE + 255) / 256;
  const int NT = (NN + 63) / 64;
  const int ET = (NE + 63) / 64;

  k_prep<<<nj * 4, 256, 0, stream>>>(jobs);
  k_prep_E<<<1, 128, 0, stream>>>(W_ee1, w1e8);
  k_prep_M<<<6 * 128, 128, 0, stream>>>(W_ee2, b_ee2, We1, mt, cvec);
  k_prep_Z<<<6 * 128, 128, 0, stream>>>(We2, be2, Wn1, wzt, bvv);
  hipMemsetAsync(count, 0, (size_t)2 * NN * 4, stream);
  hipMemsetAsync(agg, 0, (size_t)NN * HD * 4, stream);
  k_hist<<<EB, 256, 0, stream>>>(dstI, count);
  k_scan<<<1, 1024, 0, stream>>>(count, startA);
  k_scatter<<<EB, 256, 0, stream>>>(srcI, dstI, coords, startA, cursor, srcS, dstS, efS);
  k_enc_node<<<NT, 256, 0, stream>>>(x, W_ne1, b_ne1, wt_ne2, b_ne2, we1t, be1, cvec,
                                     h32, h16, Pd, Ps);

  for (int l = 0; l < 6; ++l) {
    int ln = (l + 1 < 6) ? (l + 1) : 0;  // dummy weights for last layer (doPP=0)
    k_edge<<<ET, 512, 0, stream>>>(efS, srcS, dstS, Pd, Ps, w1e8, b_ee1,
                                   mt + (size_t)l * 128 * 128, agg, ET);
    k_node<<<NT, 256, 0, stream>>>(
        h16, agg, startA, wn1t + (size_t)l * 128 * 256, bn1 + l * 128,
        wzt + (size_t)l * 128 * 128, bvv + l * 128, wn2t + (size_t)l * 128 * 128,
        bn2 + l * 128, ln_g + l * 128, ln_b + l * 128,
        we1t + (size_t)ln * 128 * 384, be1 + ln * 128, cvec + ln * 128, h32, h16,
        Pd, Ps, (l + 1 < 6) ? 1 : 0);
  }
  k_dec<<<NT, 256, 0, stream>>>(h16, wd1t, bd1, Wd2, bd2, out);
}

// Round 7
// 1257.711 us; speedup vs baseline: 1.1595x; 1.0651x over previous
//
#include <hip/hip_runtime.h>

#define NN 50000
#define NE 500000
#define HD 128

typedef _Float16 f16;
typedef _Float16 f16x8 __attribute__((ext_vector_type(8)));
typedef _Float16 f16x4 __attribute__((ext_vector_type(4)));
typedef float f32x4 __attribute__((ext_vector_type(4)));

// ---------- helpers ----------

// XOR-swizzled LDS index for a [rows][128] f16 tile (16B-chunk swizzle, no pad).
__device__ __forceinline__ int swz(int r, int c) {
  return r * HD + ((((c >> 3) ^ r) & 15) << 3) + (c & 7);
}

__device__ __forceinline__ float fast_silu(float x) {
  return x * __builtin_amdgcn_rcpf(1.0f + __expf(-x));
}

// One wave computes a 32x64 sub-tile of D(64x128) = A(64x128) @ W^T. (256-thr blocks)
__device__ __forceinline__ void gemm_wave_g(const f16* A, const f16* __restrict__ Wg,
                                            int wstride, int rowBase, int colBase,
                                            f32x4 acc[2][4]) {
  const int lane = (int)threadIdx.x & 63;
  const int m = lane & 15;
  const int q = lane >> 4;
#pragma unroll
  for (int kc = 0; kc < 4; ++kc) {
    const int pc = (((kc * 4 + q) ^ m) & 15) << 3;  // swizzled A k-chunk offset
    const int gk = (kc * 4 + q) << 3;               // linear k offset for global W
    f16x8 a0 = *(const f16x8*)(A + (rowBase + m) * HD + pc);
    f16x8 a1 = *(const f16x8*)(A + (rowBase + 16 + m) * HD + pc);
#pragma unroll
    for (int ct = 0; ct < 4; ++ct) {
      f16x8 b = *(const f16x8*)(Wg + (colBase + ct * 16 + m) * wstride + gk);
      acc[0][ct] = __builtin_amdgcn_mfma_f32_16x16x32_f16(a0, b, acc[0][ct], 0, 0, 0);
      acc[1][ct] = __builtin_amdgcn_mfma_f32_16x16x32_f16(a1, b, acc[1][ct], 0, 0, 0);
    }
  }
}

// One wave computes a 32x32 sub-tile (512-thread blocks, 8 waves over 64x128).
__device__ __forceinline__ void gemm_wave_g2(const f16* A, const f16* __restrict__ Wg,
                                             int wstride, int rowBase, int colBase,
                                             f32x4 acc[2][2]) {
  const int lane = (int)threadIdx.x & 63;
  const int m = lane & 15;
  const int q = lane >> 4;
#pragma unroll
  for (int kc = 0; kc < 4; ++kc) {
    const int pc = (((kc * 4 + q) ^ m) & 15) << 3;
    const int gk = (kc * 4 + q) << 3;
    f16x8 a0 = *(const f16x8*)(A + (rowBase + m) * HD + pc);
    f16x8 a1 = *(const f16x8*)(A + (rowBase + 16 + m) * HD + pc);
#pragma unroll
    for (int ct = 0; ct < 2; ++ct) {
      f16x8 b = *(const f16x8*)(Wg + (colBase + ct * 16 + m) * wstride + gk);
      acc[0][ct] = __builtin_amdgcn_mfma_f32_16x16x32_f16(a0, b, acc[0][ct], 0, 0, 0);
      acc[1][ct] = __builtin_amdgcn_mfma_f32_16x16x32_f16(a1, b, acc[1][ct], 0, 0, 0);
    }
  }
}

#define ZACC(acc)                                        \
  {                                                      \
    _Pragma("unroll") for (int zi = 0; zi < 2; ++zi)     \
        _Pragma("unroll") for (int zj = 0; zj < 4; ++zj) \
            acc[zi][zj] = (f32x4){0.f, 0.f, 0.f, 0.f};   \
  }

#define ZACC2(acc)                                       \
  {                                                      \
    _Pragma("unroll") for (int zi = 0; zi < 2; ++zi)     \
        _Pragma("unroll") for (int zj = 0; zj < 2; ++zj) \
            acc[zi][zj] = (f32x4){0.f, 0.f, 0.f, 0.f};   \
  }

// cooperative 64x128 f16 tile: global(row-major, stride HD) <-> swizzled LDS
template <int TPB>
__device__ __forceinline__ void stage_rows64(const f16* __restrict__ g, long r0,
                                             long lim, f16* lds) {
#pragma unroll
  for (int it = 0; it < 1024 / TPB; ++it) {
    int idx = it * TPB + (int)threadIdx.x;
    int r = idx >> 4, ck = idx & 15;
    f16x8 v = {};
    if (r0 + r < lim) v = *(const f16x8*)(g + (r0 + r) * HD + ck * 8);
    *(f16x8*)(lds + r * HD + (((ck ^ r) & 15) << 3)) = v;
  }
}
template <int TPB>
__device__ __forceinline__ void store_rows64(const f16* lds, f16* __restrict__ g,
                                             long r0, long lim) {
#pragma unroll
  for (int it = 0; it < 1024 / TPB; ++it) {
    int idx = it * TPB + (int)threadIdx.x;
    int r = idx >> 4, ck = idx & 15;
    if (r0 + r < lim)
      *(f16x8*)(g + (r0 + r) * HD + ck * 8) =
          *(const f16x8*)(lds + r * HD + (((ck ^ r) & 15) << 3));
  }
}

// ---------- weight prep (fp32 (in,out) -> f16 [out][in]) ----------
struct TJob {
  const float* src;
  f16* dst;
  int idim;
  int odim;
};
struct TJobs {
  TJob j[27];
};

__global__ __launch_bounds__(256) void k_prep(TJobs jobs) {
  int job = blockIdx.x >> 2;
  int part = blockIdx.x & 3;
  TJob J = jobs.j[job];
  int total = J.idim * J.odim;
  for (int idx = part * 256 + (int)threadIdx.x; idx < total; idx += 1024) {
    int o = idx / J.idim;
    int i = idx - o * J.idim;
    J.dst[idx] = (f16)J.src[(long)i * J.odim + o];
  }
}

// Wee1 (4x128 f32) -> f16 [128][8] zero-padded to K=8
__global__ __launch_bounds__(128) void k_prep_E(const float* __restrict__ W,
                                                f16* __restrict__ W8) {
  int t = threadIdx.x;
#pragma unroll
  for (int i = 0; i < 8; ++i) W8[t * 8 + i] = (i < 4) ? (f16)W[i * 128 + t] : (f16)0.f;
}

// ---------- folded edge-encoder weights ----------
// Mt[l][o][h] = sum_e Wee2[h][e] * We1[l][2H+e][o]   (f16, [out][in] layout)
// cv[l][o]   = sum_e b2[e]      * We1[l][2H+e][o]   (f32)
__global__ __launch_bounds__(128) void k_prep_M(const float* __restrict__ Wee2,
                                                const float* __restrict__ b2,
                                                const float* __restrict__ We1,
                                                f16* __restrict__ Mt,
                                                float* __restrict__ cv) {
  __shared__ float col[128];
  int l = blockIdx.x >> 7, o = blockIdx.x & 127;
  int t = threadIdx.x;
  col[t] = We1[((size_t)l * 384 + 256 + t) * 128 + o];
  __syncthreads();
  float s = 0.f;
#pragma unroll 8
  for (int e = 0; e < 128; ++e) s += Wee2[t * 128 + e] * col[e];
  Mt[((size_t)l * 128 + o) * 128 + t] = (f16)s;
  if (t == 0) {
    float c = 0.f;
    for (int e = 0; e < 128; ++e) c += b2[e] * col[e];
    cv[l * 128 + o] = c;
  }
}

// ---------- folded aggregation weights ----------
// WZ[l] = We2[l] @ Wn1_agg[l]  (agg rows 128..255 of Wn1), stored f16 [out][in]
// bv[l][o] = sum_j be2[l][j] * Wn1[l][128+j][o]  (f32)
__global__ __launch_bounds__(128) void k_prep_Z(const float* __restrict__ We2,
                                                const float* __restrict__ be2,
                                                const float* __restrict__ Wn1,
                                                f16* __restrict__ WZt,
                                                float* __restrict__ bve) {
  __shared__ float col[128];
  int l = blockIdx.x >> 7, o = blockIdx.x & 127;
  int t = threadIdx.x;
  col[t] = Wn1[((size_t)l * 256 + 128 + t) * 128 + o];
  __syncthreads();
  float s = 0.f;
#pragma unroll 8
  for (int j = 0; j < 128; ++j) s += We2[(size_t)l * 128 * 128 + t * 128 + j] * col[j];
  WZt[((size_t)l * 128 + o) * 128 + t] = (f16)s;
  if (t == 0) {
    float c = 0.f;
    for (int j = 0; j < 128; ++j) c += be2[l * 128 + j] * col[j];
    bve[l * 128 + o] = c;
  }
}

// ---------- counting sort by dst ----------
__global__ __launch_bounds__(256) void k_hist(const int* __restrict__ dst,
                                              int* __restrict__ count) {
  int e = blockIdx.x * 256 + threadIdx.x;
  if (e < NE) atomicAdd(&count[dst[e]], 1);
}

__global__ __launch_bounds__(1024) void k_scan(const int* __restrict__ count,
                                               int* __restrict__ startA) {
  __shared__ int lds[1024];
  const int CH = 49;  // 49*1024 >= NN
  int t = threadIdx.x;
  int b = t * CH;
  int e = b + CH < NN ? b + CH : NN;
  int s = 0;
  for (int i = b; i < e; ++i) s += count[i];
  lds[t] = s;
  __syncthreads();
  for (int off = 1; off < 1024; off <<= 1) {
    int v = (t >= off) ? lds[t - off] : 0;
    __syncthreads();
    lds[t] += v;
    __syncthreads();
  }
  int run = lds[t] - s;  // exclusive prefix of this chunk
  for (int i = b; i < e; ++i) {
    startA[i] = run;
    run += count[i];
  }
  if (t == 0) startA[NN] = NE;
}

__global__ __launch_bounds__(256) void k_scatter(const int* __restrict__ src,
                                                 const int* __restrict__ dst,
                                                 const float* __restrict__ coords,
                                                 const int* __restrict__ startA,
                                                 int* __restrict__ cursor,
                                                 int* __restrict__ srcS,
                                                 int* __restrict__ dstS,
                                                 f16* __restrict__ efS) {
  int e = blockIdx.x * 256 + threadIdx.x;
  if (e >= NE) return;
  int s = src[e];
  int n = dst[e];
  int pos = startA[n] + atomicAdd(&cursor[n], 1);
  srcS[pos] = s;
  dstS[pos] = n;
  float rx = coords[n * 3] - coords[s * 3];
  float ry = coords[n * 3 + 1] - coords[s * 3 + 1];
  float rz = coords[n * 3 + 2] - coords[s * 3 + 2];
  float nr = sqrtf(rx * rx + ry * ry + rz * rz);
  f16x8 v = {};
  v[0] = (f16)rx;
  v[1] = (f16)ry;
  v[2] = (f16)rz;
  v[3] = (f16)nr;
  *(f16x8*)(efS + (long)pos * 8) = v;
}

// ---------- node encoder: h = silu(x@Wne1+b)@Wne2+b  (f16 h only) ----------
__global__ __launch_bounds__(256, 4) void k_enc_node(
    const float* __restrict__ x, const float* __restrict__ W1,
    const float* __restrict__ b1, const f16* __restrict__ W2t,
    const float* __restrict__ b2, f16* __restrict__ h16) {
  __shared__ __align__(16) f16 lds_A[64 * HD];
  __shared__ __align__(16) f16 lds_O[64 * HD];
  float* lds_x = (float*)lds_O;  // alias O
  long r0 = (long)blockIdx.x * 64;
  int t = threadIdx.x;
  int wv = t >> 6, lane = t & 63, nn = lane & 15, q = lane >> 4;
  int rowBase = (wv >> 1) * 32, colBase = (wv & 1) * 64;

  if (t < 192) {
    long i = r0 * 3 + t;
    lds_x[t] = (i < (long)NN * 3) ? x[i] : 0.f;
  }
  __syncthreads();

  for (int it = 0; it < 32; ++it) {
    int idx = it * 256 + t;
    int r = idx >> 7, c = idx & 127;
    float a = b1[c];
    a += lds_x[r * 3 + 0] * W1[0 * HD + c];
    a += lds_x[r * 3 + 1] * W1[1 * HD + c];
    a += lds_x[r * 3 + 2] * W1[2 * HD + c];
    lds_A[swz(r, c)] = (f16)fast_silu(a);
  }
  __syncthreads();

  f32x4 acc[2][4];
  ZACC(acc);
  gemm_wave_g(lds_A, W2t, HD, rowBase, colBase, acc);
#pragma unroll
  for (int rt = 0; rt < 2; ++rt)
#pragma unroll
    for (int ct = 0; ct < 4; ++ct)
#pragma unroll
      for (int rg = 0; rg < 4; ++rg) {
        int row = rowBase + rt * 16 + q * 4 + rg;
        int col = colBase + ct * 16 + nn;
        lds_O[swz(row, col)] = (f16)(acc[rt][ct][rg] + b2[col]);
      }
  __syncthreads();
  store_rows64<256>(lds_O, h16, r0, NN);
}

// ---------- per-layer: Pd = h@W_d + be1 + cv, Ps = h@W_s  (512 thr) ----------
__global__ __launch_bounds__(512, 8) void k_pp(const f16* __restrict__ h16,
                                               const f16* __restrict__ We1t,
                                               const float* __restrict__ be1,
                                               const float* __restrict__ cvec,
                                               f16* __restrict__ Pd,
                                               f16* __restrict__ Ps) {
  __shared__ __align__(16) f16 lds_A[64 * HD];
  __shared__ __align__(16) f16 lds_O[64 * HD];
  long r0 = (long)blockIdx.x * 64;
  int t = threadIdx.x;
  int wv = t >> 6, lane = t & 63, nn = lane & 15, q = lane >> 4;
  int rowBase = (wv >> 2) * 32, colBase = (wv & 3) * 32;

  stage_rows64<512>(h16, r0, NN, lds_A);
  __syncthreads();

  f32x4 acc[2][2];
  ZACC2(acc);
  gemm_wave_g2(lds_A, We1t, 384, rowBase, colBase, acc);  // W_d^T (k 0..127)
#pragma unroll
  for (int rt = 0; rt < 2; ++rt)
#pragma unroll
    for (int ct = 0; ct < 2; ++ct)
#pragma unroll
      for (int rg = 0; rg < 4; ++rg) {
        int row = rowBase + rt * 16 + q * 4 + rg;
        int col = colBase + ct * 16 + nn;
        lds_O[swz(row, col)] = (f16)(acc[rt][ct][rg] + be1[col] + cvec[col]);
      }
  __syncthreads();
  store_rows64<512>(lds_O, Pd, r0, NN);

  ZACC2(acc);
  gemm_wave_g2(lds_A, We1t + 128, 384, rowBase, colBase, acc);  // W_s^T
  __syncthreads();  // all waves done reading lds_O (Pd store) before overwrite
#pragma unroll
  for (int rt = 0; rt < 2; ++rt)
#pragma unroll
    for (int ct = 0; ct < 2; ++ct)
#pragma unroll
      for (int rg = 0; rg < 4; ++rg) {
        int row = rowBase + rt * 16 + q * 4 + rg;
        int col = colBase + ct * 16 + nn;
        lds_O[swz(row, col)] = (f16)acc[rt][ct][rg];
      }
  __syncthreads();
  store_rows64<512>(lds_O, Ps, r0, NN);
}

// ---------- per-layer edge kernel (512 thr, 8 waves) ----------
// z = silu(silu2@Mt + Pd[dst]+Ps[src]); silu2 computed via K=8-packed MFMA.
// Segmented z-sum: plain store for quarter-interior runs, atomic at boundaries.
__global__ __launch_bounds__(512, 8) void k_edge(
    const f16* __restrict__ efS, const int* __restrict__ srcS,
    const int* __restrict__ dstS, const f16* __restrict__ Pd,
    const f16* __restrict__ Ps, const f16* __restrict__ W1e8,
    const float* __restrict__ b1, const f16* __restrict__ Mt,
    float* __restrict__ zs, int nwg) {
  __shared__ __align__(16) f16 lds_A[64 * HD];  // silu2
  __shared__ __align__(16) f16 lds_P[64 * HD];  // pdps, then z
  __shared__ int dstL[64];
  // bijective XCD-chunked swizzle: consecutive logical blocks -> same XCD
  int orig = blockIdx.x;
  int xcd = orig & 7, loc = orig >> 3;
  int qq = nwg >> 3, rr = nwg & 7;
  int wg = (xcd < rr ? xcd * (qq + 1) : rr * (qq + 1) + (xcd - rr) * qq) + loc;
  long e0 = (long)wg * 64;
  int t = threadIdx.x;
  int lane = t & 63, nn = lane & 15, q = lane >> 4;
  int wv = t >> 6;
  int rowBase = (wv >> 2) * 32, colBase = (wv & 3) * 32;

  if (t < 64) {
    long e = e0 + t;
    dstL[t] = (e < NE) ? dstS[e] : -1;
  }

  // silu2 A/B fragments: only q==0 lanes carry k=0..7 (ef padded 4->8)
  f16x8 ea0 = {}, ea1 = {}, eb0 = {}, eb1 = {};
  if (q == 0) {
    long er0 = e0 + rowBase + nn;
    long er1 = er0 + 16;
    if (er0 < NE) ea0 = *(const f16x8*)(efS + er0 * 8);
    if (er1 < NE) ea1 = *(const f16x8*)(efS + er1 * 8);
    eb0 = *(const f16x8*)(W1e8 + (colBase + nn) * 8);
    eb1 = *(const f16x8*)(W1e8 + (colBase + 16 + nn) * 8);
  }
  f32x4 sacc[2][2];
  ZACC2(sacc);
  sacc[0][0] = __builtin_amdgcn_mfma_f32_16x16x32_f16(ea0, eb0, sacc[0][0], 0, 0, 0);
  sacc[1][0] = __builtin_amdgcn_mfma_f32_16x16x32_f16(ea1, eb0, sacc[1][0], 0, 0, 0);
  sacc[0][1] = __builtin_amdgcn_mfma_f32_16x16x32_f16(ea0, eb1, sacc[0][1], 0, 0, 0);
  sacc[1][1] = __builtin_amdgcn_mfma_f32_16x16x32_f16(ea1, eb1, sacc[1][1], 0, 0, 0);

  // pdps gathers -> registers (latency hidden under silu2 epilogue)
  int rr0 = t >> 4, rr1 = 32 + (t >> 4);
  int ck = t & 15;
  f16x8 pa0 = {}, pb0 = {}, pa1 = {}, pb1 = {};
  {
    long e = e0 + rr0;
    if (e < NE) {
      int d = dstS[e], s = srcS[e];
      pa0 = *(const f16x8*)(Pd + (long)d * HD + ck * 8);
      pb0 = *(const f16x8*)(Ps + (long)s * HD + ck * 8);
    }
  }
  {
    long e = e0 + rr1;
    if (e < NE) {
      int d = dstS[e], s = srcS[e];
      pa1 = *(const f16x8*)(Pd + (long)d * HD + ck * 8);
      pb1 = *(const f16x8*)(Ps + (long)s * HD + ck * 8);
    }
  }

  // silu2 epilogue -> lds_A (swizzled, f16)
  {
    float b1v0 = b1[colBase + nn], b1v1 = b1[colBase + 16 + nn];
#pragma unroll
    for (int rt = 0; rt < 2; ++rt)
#pragma unroll
      for (int ct = 0; ct < 2; ++ct) {
        float bb = ct ? b1v1 : b1v0;
        int col = colBase + ct * 16 + nn;
#pragma unroll
        for (int rg = 0; rg < 4; ++rg) {
          int row = rowBase + rt * 16 + q * 4 + rg;
          lds_A[swz(row, col)] = (f16)fast_silu(sacc[rt][ct][rg] + bb);
        }
      }
  }
  // pdps -> lds_P
  {
    f16x8 v = pa0 + pb0;
    *(f16x8*)(lds_P + rr0 * HD + (((ck ^ rr0) & 15) << 3)) = v;
  }
  {
    f16x8 v = pa1 + pb1;
    *(f16x8*)(lds_P + rr1 * HD + (((ck ^ rr1) & 15) << 3)) = v;
  }
  __syncthreads();

  f32x4 acc[2][2];
  ZACC2(acc);
  gemm_wave_g2(lds_A, Mt, HD, rowBase, colBase, acc);  // silu2 @ Mt[l]

  // z = silu(acc + pdps) in-place into OWN 32x32 region of lds_P (cv in Pd)
#pragma unroll
  for (int rt = 0; rt < 2; ++rt)
#pragma unroll
    for (int ct = 0; ct < 2; ++ct)
#pragma unroll
      for (int rg = 0; rg < 4; ++rg) {
        int row = rowBase + rt * 16 + q * 4 + rg;
        int col = colBase + ct * 16 + nn;
        float v = acc[rt][ct][rg] + (float)lds_P[swz(row, col)];
        lds_P[swz(row, col)] = (f16)fast_silu(v);
      }
  __syncthreads();

  // segmented z-sum over sorted dst runs; quarter-interior runs: plain store
  {
    int c = t & 127, qt = t >> 7;
    int rb = qt * 16;
    int dfirst = dstL[rb], dlast = dstL[rb + 15];
    int prev = dfirst;
    float sum = 0.f;
    for (int r = rb; r < rb + 16; ++r) {
      int d = dstL[r];
      if (d != prev) {
        if (prev >= 0) {
          if (prev == dfirst || prev == dlast)
            atomicAdd(&zs[(long)prev * HD + c], sum);
          else
            zs[(long)prev * HD + c] = sum;  // sole writer for interior run
        }
        sum = 0.f;
        prev = d;
      }
      sum += (float)lds_P[swz(r, c)];
    }
    if (prev >= 0) atomicAdd(&zs[(long)prev * HD + c], sum);
  }
}

// ---------- per-layer node kernel (256 thr): upd MLP + residual (from staged
// h16 tile in LDS — no f32 h copy) + LayerNorm ----------
__global__ __launch_bounds__(256, 4) void k_node(
    const f16* __restrict__ h16in, float* __restrict__ zsum,
    const int* __restrict__ startA, const f16* __restrict__ Wn1t,
    const float* __restrict__ bn1, const f16* __restrict__ WZt,
    const float* __restrict__ bve, const f16* __restrict__ Wn2t,
    const float* __restrict__ bn2, const float* __restrict__ lg,
    const float* __restrict__ lb, f16* __restrict__ h16out) {
  __shared__ __align__(16) f16 lds_A[64 * HD];  // h, then y
  __shared__ __align__(16) f16 lds_B[64 * HD];  // zbar, then z
  __shared__ float lds_s[512];
  __shared__ float degf[64];
  long r0 = (long)blockIdx.x * 64;
  int t = threadIdx.x;
  int wv = t >> 6, lane = t & 63, nn = lane & 15, q = lane >> 4;
  int rowBase = (wv >> 1) * 32, colBase = (wv & 1) * 64;

  stage_rows64<256>(h16in, r0, NN, lds_A);
  // zbar = zsum / max(deg,1) -> f16 ; zero zsum for next layer
#pragma unroll
  for (int it = 0; it < 8; ++it) {
    int idx = it * 256 + t;
    int r = idx >> 5, c4 = (idx & 31) * 4;
    long nr = r0 + r;
    f16x4 v = {};
    if (nr < NN) {
      float deg = (float)(startA[nr + 1] - startA[nr]);
      float inv = __builtin_amdgcn_rcpf(fmaxf(deg, 1.0f));
      float4 a = *(const float4*)(zsum + nr * HD + c4);
      *(float4*)(zsum + nr * HD + c4) = (float4){0.f, 0.f, 0.f, 0.f};
      v[0] = (f16)(a.x * inv);
      v[1] = (f16)(a.y * inv);
      v[2] = (f16)(a.z * inv);
      v[3] = (f16)(a.w * inv);
      if (c4 == 0) degf[r] = deg > 0.f ? 1.f : 0.f;
    } else if (c4 == 0) {
      degf[r] = 0.f;
    }
    *(f16x4*)(lds_B + swz(r, c4)) = v;
  }
  __syncthreads();

  f32x4 acc[2][4];
  ZACC(acc);
  gemm_wave_g(lds_A, Wn1t, 256, rowBase, colBase, acc);  // h part
  gemm_wave_g(lds_B, WZt, HD, rowBase, colBase, acc);    // zbar part (We2 folded)
  __syncthreads();  // all waves done reading lds_B before z overwrite

  // z = silu(acc + bn1 + [deg>0]*bv) -> lds_B
#pragma unroll
  for (int rt = 0; rt < 2; ++rt)
#pragma unroll
    for (int ct = 0; ct < 4; ++ct)
#pragma unroll
      for (int rg = 0; rg < 4; ++rg) {
        int row = rowBase + rt * 16 + q * 4 + rg;
        int col = colBase + ct * 16 + nn;
        lds_B[swz(row, col)] =
            (f16)fast_silu(acc[rt][ct][rg] + bn1[col] + degf[row] * bve[col]);
      }
  __syncthreads();

  ZACC(acc);
  gemm_wave_g(lds_B, Wn2t, HD, rowBase, colBase, acc);

  // residual (from staged h16 tile in lds_A) + LN stats
  float vv[2][4][4];
  float s1[8], s2[8];
#pragma unroll
  for (int i = 0; i < 8; ++i) {
    s1[i] = 0.f;
    s2[i] = 0.f;
  }
#pragma unroll
  for (int rt = 0; rt < 2; ++rt)
#pragma unroll
    for (int ct = 0; ct < 4; ++ct)
#pragma unroll
      for (int rg = 0; rg < 4; ++rg) {
        int row = rowBase + rt * 16 + q * 4 + rg;
        int col = colBase + ct * 16 + nn;
        float hv = (float)lds_A[swz(row, col)];  // OOB rows staged as 0
        float v = acc[rt][ct][rg] + bn2[col] + hv;
        vv[rt][ct][rg] = v;
        s1[rt * 4 + rg] += v;
        s2[rt * 4 + rg] += v * v;
      }
#pragma unroll
  for (int msk = 1; msk <= 8; msk <<= 1) {
#pragma unroll
    for (int i = 0; i < 8; ++i) {
      s1[i] += __shfl_xor(s1[i], msk, 64);
      s2[i] += __shfl_xor(s2[i], msk, 64);
    }
  }
  int ch = wv & 1;
  if (nn == 0) {
#pragma unroll
    for (int rt = 0; rt < 2; ++rt)
#pragma unroll
      for (int rg = 0; rg < 4; ++rg) {
        int row = rowBase + rt * 16 + q * 4 + rg;
        lds_s[row * 2 + ch] = s1[rt * 4 + rg];
        lds_s[256 + row * 2 + ch] = s2[rt * 4 + rg];
      }
  }
  __syncthreads();
#pragma unroll
  for (int rt = 0; rt < 2; ++rt)
#pragma unroll
    for (int ct = 0; ct < 4; ++ct)
#pragma unroll
      for (int rg = 0; rg < 4; ++rg) {
        int row = rowBase + rt * 16 + q * 4 + rg;
        int col = colBase + ct * 16 + nn;
        float S1 = lds_s[row * 2] + lds_s[row * 2 + 1];
        float S2 = lds_s[256 + row * 2] + lds_s[256 + row * 2 + 1];
        float mean = S1 * (1.0f / 128.0f);
        float var = S2 * (1.0f / 128.0f) - mean * mean;
        float rstd = rsqrtf(var + 1e-5f);
        float y = (vv[rt][ct][rg] - mean) * rstd * lg[col] + lb[col];
        lds_A[swz(row, col)] = (f16)y;
      }
  __syncthreads();
  store_rows64<256>(lds_A, h16out, r0, NN);
}

// ---------- decoder ----------
__global__ __launch_bounds__(256, 4) void k_dec(
    const f16* __restrict__ h16, const f16* __restrict__ Wd1t,
    const float* __restrict__ bd1, const float* __restrict__ Wd2,
    const float* __restrict__ bd2, float* __restrict__ out) {
  __shared__ __align__(16) f16 lds_A[64 * HD];
  __shared__ __align__(16) f16 lds_O[64 * HD];
  long r0 = (long)blockIdx.x * 64;
  int t = threadIdx.x;
  int wv = t >> 6, lane = t & 63, nn = lane & 15, q = lane >> 4;
  int rowBase = (wv >> 1) * 32, colBase = (wv & 1) * 64;

  stage_rows64<256>(h16, r0, NN, lds_A);
  __syncthreads();

  f32x4 acc[2][4];
  ZACC(acc);
  gemm_wave_g(lds_A, Wd1t, HD, rowBase, colBase, acc);
#pragma unroll
  for (int rt = 0; rt < 2; ++rt)
#pragma unroll
    for (int ct = 0; ct < 4; ++ct)
#pragma unroll
      for (int rg = 0; rg < 4; ++rg) {
        int row = rowBase + rt * 16 + q * 4 + rg;
        int col = colBase + ct * 16 + nn;
        lds_O[swz(row, col)] = (f16)fast_silu(acc[rt][ct][rg] + bd1[col]);
      }
  __syncthreads();

  for (int idx = t; idx < 64 * 9; idx += 256) {
    int r = idx / 9;
    int o = idx - r * 9;
    long nr = r0 + r;
    if (nr < NN) {
      float a = bd2[o];
      for (int k = 0; k < 128; ++k) a += (float)lds_O[swz(r, k)] * Wd2[k * 9 + o];
      out[nr * 9 + o] = a;
    }
  }
}

// ---------- launch ----------
extern "C" void kernel_launch(void* const* d_in, const int* in_sizes, int n_in,
                              void* d_out, int out_size, void* d_ws, size_t ws_size,
                              hipStream_t stream) {
  (void)in_sizes;
  (void)n_in;
  (void)out_size;
  (void)ws_size;
  const float* x = (const float*)d_in[0];
  const float* coords = (const float*)d_in[1];
  const int* ei = (const int*)d_in[2];
  const float* W_ne1 = (const float*)d_in[3];
  const float* b_ne1 = (const float*)d_in[4];
  const float* W_ne2 = (const float*)d_in[5];
  const float* b_ne2 = (const float*)d_in[6];
  const float* W_ee1 = (const float*)d_in[7];
  const float* b_ee1 = (const float*)d_in[8];
  const float* W_ee2 = (const float*)d_in[9];
  const float* b_ee2 = (const float*)d_in[10];
  const float* We1 = (const float*)d_in[11];
  const float* be1 = (const float*)d_in[12];
  const float* We2 = (const float*)d_in[13];
  const float* be2 = (const float*)d_in[14];
  const float* Wn1 = (const float*)d_in[15];
  const float* bn1 = (const float*)d_in[16];
  const float* Wn2 = (const float*)d_in[17];
  const float* bn2 = (const float*)d_in[18];
  const float* ln_g = (const float*)d_in[19];
  const float* ln_b = (const float*)d_in[20];
  const float* Wd1 = (const float*)d_in[21];
  const float* bd1 = (const float*)d_in[22];
  const float* Wd2 = (const float*)d_in[23];
  const float* bd2 = (const float*)d_in[24];
  float* out = (float*)d_out;

  char* ws = (char*)d_ws;
  size_t off = 0;
  auto alloc = [&](size_t bytes) -> void* {
    void* p = ws + off;
    off = (off + bytes + 255) & ~(size_t)255;
    return p;
  };
  f16* h16 = (f16*)alloc((size_t)NN * HD * 2);
  f16* h16b = (f16*)alloc((size_t)NN * HD * 2);
  f16* Pd = (f16*)alloc((size_t)NN * HD * 2);
  f16* Ps = (f16*)alloc((size_t)NN * HD * 2);
  float* agg = (float*)alloc((size_t)NN * HD * 4);
  f16* efS = (f16*)alloc((size_t)NE * 8 * 2);
  int* srcS = (int*)alloc((size_t)NE * 4);
  int* dstS = (int*)alloc((size_t)NE * 4);
  int* count = (int*)alloc((size_t)2 * NN * 4);  // count + cursor (contiguous)
  int* cursor = count + NN;
  int* startA = (int*)alloc((size_t)(NN + 1) * 4);
  f16* wt_ne2 = (f16*)alloc(128 * 128 * 2);
  f16* we1t = (f16*)alloc((size_t)6 * 128 * 384 * 2);
  f16* wn1t = (f16*)alloc((size_t)6 * 128 * 256 * 2);
  f16* wn2t = (f16*)alloc((size_t)6 * 128 * 128 * 2);
  f16* wd1t = (f16*)alloc(128 * 128 * 2);
  f16* mt = (f16*)alloc((size_t)6 * 128 * 128 * 2);
  float* cvec = (float*)alloc((size_t)6 * 128 * 4);
  f16* wzt = (f16*)alloc((size_t)6 * 128 * 128 * 2);
  float* bvv = (float*)alloc((size_t)6 * 128 * 4);
  f16* w1e8 = (f16*)alloc(128 * 8 * 2);

  TJobs jobs;
  int nj = 0;
  jobs.j[nj++] = {W_ne2, wt_ne2, 128, 128};
  for (int l = 0; l < 6; ++l)
    jobs.j[nj++] = {We1 + (size_t)l * 384 * 128, we1t + (size_t)l * 128 * 384, 384, 128};
  for (int l = 0; l < 6; ++l)
    jobs.j[nj++] = {Wn1 + (size_t)l * 256 * 128, wn1t + (size_t)l * 128 * 256, 256, 128};
  for (int l = 0; l < 6; ++l)
    jobs.j[nj++] = {Wn2 + (size_t)l * 128 * 128, wn2t + (size_t)l * 128 * 128, 128, 128};
  jobs.j[nj++] = {Wd1, wd1t, 128, 128};

  const int* srcI = ei;       // edge_index[0]
  const int* dstI = ei + NE;  // edge_index[1]
  const int EB = (NE + 255) / 256;
  const int NT = (NN + 63) / 64;
  const int ET = (NE + 63) / 64;

  k_prep<<<nj * 4, 256, 0, stream>>>(jobs);
  k_prep_E<<<1, 128, 0, stream>>>(W_ee1, w1e8);
  k_prep_M<<<6 * 128, 128, 0, stream>>>(W_ee2, b_ee2, We1, mt, cvec);
  k_prep_Z<<<6 * 128, 128, 0, stream>>>(We2, be2, Wn1, wzt, bvv);
  hipMemsetAsync(count, 0, (size_t)2 * NN * 4, stream);
  hipMemsetAsync(agg, 0, (size_t)NN * HD * 4, stream);
  k_hist<<<EB, 256, 0, stream>>>(dstI, count);
  k_scan<<<1, 1024, 0, stream>>>(count, startA);
  k_scatter<<<EB, 256, 0, stream>>>(srcI, dstI, coords, startA, cursor, srcS, dstS, efS);
  k_enc_node<<<NT, 256, 0, stream>>>(x, W_ne1, b_ne1, wt_ne2, b_ne2, h16);

  f16* hin = h16;
  f16* hout = h16b;
  for (int l = 0; l < 6; ++l) {
    k_pp<<<NT, 512, 0, stream>>>(hin, we1t + (size_t)l * 128 * 384, be1 + l * 128,
                                 cvec + l * 128, Pd, Ps);
    k_edge<<<ET, 512, 0, stream>>>(efS, srcS, dstS, Pd, Ps, w1e8, b_ee1,
                                   mt + (size_t)l * 128 * 128, agg, ET);
    k_node<<<NT, 256, 0, stream>>>(hin, agg, startA, wn1t + (size_t)l * 128 * 256,
                                   bn1 + l * 128, wzt + (size_t)l * 128 * 128,
                                   bvv + l * 128, wn2t + (size_t)l * 128 * 128,
                                   bn2 + l * 128, ln_g + l * 128, ln_b + l * 128, hout);
    f16* tmp = hin;
    hin = hout;
    hout = tmp;
  }
  k_dec<<<NT, 256, 0, stream>>>(hin, wd1t, bd1, Wd2, bd2, out);
}